// Round 1
// baseline (963.425 us; speedup 1.0000x reference)
//
#include <hip/hip_runtime.h>
#include <hip/hip_fp16.h>
#include <hip/hip_cooperative_groups.h>
#include <cstdint>
#include <cstddef>

namespace cg = cooperative_groups;

#define NNODES 8192
#define NEDGES 262144
#define SMEM_BYTES 10496   // max over phases: gemm As(5120)+Bs(5120)+cs(256)

typedef _Float16 f16x8 __attribute__((ext_vector_type(8)));
typedef _Float16 h2v   __attribute__((ext_vector_type(2)));
typedef float    f32x4 __attribute__((ext_vector_type(4)));

__device__ __forceinline__ float leaky(float v){ return v > 0.f ? v : 0.01f*v; }

__device__ __forceinline__ unsigned fmap(float f){
  unsigned u = __float_as_uint(f);
  return (u & 0x80000000u) ? ~u : (u | 0x80000000u);
}
__device__ __forceinline__ float funmap(unsigned u){
  return (u & 0x80000000u) ? __uint_as_float(u & 0x7FFFFFFFu) : __uint_as_float(~u);
}
__device__ __forceinline__ h2v as_h2(unsigned u){
  union{ unsigned x; h2v h; } c; c.x = u; return c.h;
}

// ---------------- all device pointers in one struct (single kernel arg) ----------
struct GP {
  const float *x; const int *ei;
  const float *W1,*b1,*W2,*b2,*W3,*b3,*Wk,*bk,*Wq,*bq,*Wr,*br,*lng,*lnb,*Wf,*bfv;
  float* out;
  __half *xh,*xw1h,*h1h,*h1ah,*h2h,*qth,*gh,*hw3h;
  float *resid,*dinv,*sw3;
  __half *Wqh,*Wkh,*Wqkt,*Wrt,*W1t,*W2t,*W3t;
  float *bqk,*wb,*s0p;
  int *degc,*degr,*ptrc,*ptrr,*curc,*curr,*csrc,*csrd;
  unsigned* poolpart;
};

// ================= pre unit: conversions / transposes / zeroing / small vectors ====
// [0,1024): x->xh vec4 | [1024,1088): Wq | [1088,1152): Wk | [1152,1184): Wrt
// [1184,1248): W1t | [1248,1376): W2t | [1376,1440): W3t
// [1440,1504): zero degc/degr | [1504,1520): zero poolpart | 1520: zero sw3
// [1521,1777): smallvec (coalesced): bqk[c]=Wk_row_c.bq, wb[c]=Wq_row_c.bk; c0 adds s0
__device__ __forceinline__ void pre_unit(const GP& p, int b, char* smem){
  int t = threadIdx.x;
  if (b < 1024){
    int base = (b*256 + t)*4;
    float4 xv = *(const float4*)(p.x + base);
    uint2 o;
    *(__half2*)&o.x = __floats2half2_rn(xv.x, xv.y);
    *(__half2*)&o.y = __floats2half2_rn(xv.z, xv.w);
    *(uint2*)(p.xh + base) = o;
  } else if (b < 1088){
    int base = ((b-1024)*256 + t)*4;
    float4 v = *(const float4*)(p.Wq + base);
    uint2 o;
    *(__half2*)&o.x = __floats2half2_rn(v.x, v.y);
    *(__half2*)&o.y = __floats2half2_rn(v.z, v.w);
    *(uint2*)(p.Wqh + base) = o;
  } else if (b < 1152){
    int base = ((b-1088)*256 + t)*4;
    float4 v = *(const float4*)(p.Wk + base);
    uint2 o;
    *(__half2*)&o.x = __floats2half2_rn(v.x, v.y);
    *(__half2*)&o.y = __floats2half2_rn(v.z, v.w);
    *(uint2*)(p.Wkh + base) = o;
  } else if (b < 1184){         // Wr[128][64] -> Wrt[64][128]
    int idx = (b-1152)*256 + t;
    int nn = idx >> 7, k = idx & 127;
    p.Wrt[idx] = __float2half(p.Wr[k*64 + nn]);
  } else if (b < 1248){         // W1[128][128] -> W1t[128][128]
    int idx = (b-1184)*256 + t;
    int nn = idx >> 7, k = idx & 127;
    p.W1t[idx] = __float2half(p.W1[k*128 + nn]);
  } else if (b < 1376){         // W2[128][256] -> W2t[256][128]
    int idx = (b-1248)*256 + t;
    int nn = idx >> 7, k = idx & 127;
    p.W2t[idx] = __float2half(p.W2[k*256 + nn]);
  } else if (b < 1440){         // W3[256][64] -> W3t[64][256]
    int idx = (b-1376)*256 + t;
    int nn = idx >> 8, k = idx & 255;
    p.W3t[idx] = __float2half(p.W3[k*64 + nn]);
  } else if (b < 1504){
    int idx = (b-1440)*256 + t;
    if (idx < 8192) p.degc[idx]=0; else p.degr[idx-8192]=0;
  } else if (b < 1520){
    p.poolpart[(b-1504)*256 + t] = 0u;
  } else if (b == 1520){
    if (t < 64) p.sw3[t]=0.f;
  } else {                      // smallvec: coalesced row read + block reduce
    int c = b - 1521;
    float* ra = (float*)smem; float* rb = ra + 256; float* rc = rb + 256;
    ra[t] = p.Wk[c*256 + t] * p.bq[t];
    rb[t] = p.Wq[c*256 + t] * p.bk[t];
    if (c == 0) rc[t] = p.bq[t]*p.bk[t];
    __syncthreads();
    for (int off=128; off; off>>=1){
      if (t < off){
        ra[t] += ra[t+off];
        rb[t] += rb[t+off];
        if (c == 0) rc[t] += rc[t+off];
      }
      __syncthreads();
    }
    if (t == 0){
      p.bqk[c] = ra[0];
      p.wb[c]  = rb[0];
      if (c == 0) p.s0p[0] = rc[0];
    }
    __syncthreads();
  }
}

// ---------------- MFMA GEMM tile (device): C64x64 = A[.,K] @ Bt[.,K]^T ----------------
__device__ __forceinline__ void gemm_tile(const __half* __restrict__ A,
    const __half* __restrict__ Bt, const float* __restrict__ bias,
    float* __restrict__ Cf, __half* __restrict__ Ch, float* __restrict__ csum,
    int K, int N, int act, int bx, int by,
    _Float16 (*As)[40], _Float16 (*Bs)[40], float* cs){
  int t = threadIdx.x, w = t>>6, lane = t&63;
  int m0 = bx*64, n0 = by*64;
  int quad = lane>>4, l15 = lane&15;
  int srow = t>>2, soff = (t&3)*8;
  f32x4 acc0 = {0.f,0.f,0.f,0.f}, acc1 = acc0, acc2 = acc0, acc3 = acc0;
  for (int k0 = 0; k0 < K; k0 += 32){
    *(uint4*)&As[srow][soff] = *(const uint4*)(A  + (size_t)(m0+srow)*K + k0 + soff);
    *(uint4*)&Bs[srow][soff] = *(const uint4*)(Bt + (size_t)(n0+srow)*K + k0 + soff);
    __syncthreads();
    f16x8 af = *(const f16x8*)&As[w*16 + l15][quad*8];
    f16x8 b0 = *(const f16x8*)&Bs[ 0 + l15][quad*8];
    f16x8 b1 = *(const f16x8*)&Bs[16 + l15][quad*8];
    f16x8 b2 = *(const f16x8*)&Bs[32 + l15][quad*8];
    f16x8 b3 = *(const f16x8*)&Bs[48 + l15][quad*8];
    acc0 = __builtin_amdgcn_mfma_f32_16x16x32_f16(af, b0, acc0, 0,0,0);
    acc1 = __builtin_amdgcn_mfma_f32_16x16x32_f16(af, b1, acc1, 0,0,0);
    acc2 = __builtin_amdgcn_mfma_f32_16x16x32_f16(af, b2, acc2, 0,0,0);
    acc3 = __builtin_amdgcn_mfma_f32_16x16x32_f16(af, b3, acc3, 0,0,0);
    __syncthreads();
  }
  f32x4 accs[4] = {acc0, acc1, acc2, acc3};
  if (csum){
    if (t < 64) cs[t] = 0.f;
    __syncthreads();
    #pragma unroll
    for (int nt=0; nt<4; ++nt){
      float pp = accs[nt][0]+accs[nt][1]+accs[nt][2]+accs[nt][3];
      atomicAdd(&cs[nt*16 + l15], pp);
    }
    __syncthreads();
    if (t < 64) atomicAdd(&csum[n0 + t], cs[t]);
    __syncthreads();
  }
  #pragma unroll
  for (int nt=0; nt<4; ++nt){
    int col = n0 + nt*16 + l15;
    float bv = bias ? bias[col] : 0.f;
    #pragma unroll
    for (int r=0;r<4;r++){
      int row = m0 + w*16 + quad*4 + r;
      float v = accs[nt][r] + bv;
      if (act) v = leaky(v);
      if (Cf) Cf[(size_t)row*N + col] = v;
      if (Ch) Ch[(size_t)row*N + col] = __float2half(v);
    }
  }
}

// -------- 256-thread exclusive scan + prep (side 0: col w/ dinv; side 1: row) --------
// 32 nodes per thread, two passes over deg (L2-hot); wave scan + 4-wave LDS combine
__device__ __forceinline__ void scan256(const GP& p, int side, char* smem){
  const int n = NNODES;
  const int* deg = side ? p.degr : p.degc;
  int* ptr = side ? p.ptrr : p.ptrc;
  int* cur = side ? p.curr : p.curc;
  int t = threadIdx.x, lane = t & 63, wid = t >> 6;
  int base = t*32;
  int s = 0;
  #pragma unroll 4
  for (int q=0;q<32;q++) s += deg[base+q];
  int sc = s;
  #pragma unroll
  for (int o=1;o<64;o<<=1){ int v = __shfl_up(sc, o, 64); if (lane >= o) sc += v; }
  int* wsum = (int*)smem;
  if (lane==63) wsum[wid] = sc;
  __syncthreads();
  int add = 0;
  #pragma unroll
  for (int k=0;k<3;k++) if (k < wid) add += wsum[k];
  int run = add + sc - s;
  for (int q=0;q<32;q++){
    int d = deg[base+q];
    ptr[base+q] = run;
    cur[base+q] = run;
    if (!side) p.dinv[base+q] = rsqrtf((float)(d+1));
    run += d;
  }
  if (t==255) ptr[n] = run;
  __syncthreads();
}

// -------- GCN aggregation, F=128: 4 waves split edges, ILP-4, optional bias+leaky ----
__device__ __forceinline__ void agg128_unit(const __half* __restrict__ in,
    const int* __restrict__ ptr, const int* __restrict__ src,
    const float* __restrict__ dinv, __half* __restrict__ outp,
    const float* __restrict__ bias, int act, int c, char* smem){
  int t = threadIdx.x, w = t>>6, lane = t&63;
  float dc = dinv[c];
  float2 acc = make_float2(0.f, 0.f);
  int e0 = ptr[c], e1 = ptr[c+1];
  for (int eb = e0 + w*4; eb < e1; eb += 16){
    int m = e1 - eb; if (m > 4) m = 4;
    int r[4];
    #pragma unroll
    for (int u=0;u<4;u++) r[u] = src[(u<m) ? eb+u : eb];
    float sc[4]; __half2 hv[4];
    #pragma unroll
    for (int u=0;u<4;u++){
      sc[u] = dinv[r[u]];
      hv[u] = *(const __half2*)(in + (size_t)r[u]*128 + lane*2);
    }
    #pragma unroll
    for (int u=0;u<4;u++){
      if (u < m){
        float2 h = __half22float2(hv[u]);
        acc.x = fmaf(sc[u], h.x, acc.x);
        acc.y = fmaf(sc[u], h.y, acc.y);
      }
    }
  }
  float2 (*red)[64] = (float2(*)[64])smem;
  red[w][lane] = acc;
  __syncthreads();
  if (w == 0){
    float2 s = red[0][lane];
    float2 b1 = red[1][lane], b2 = red[2][lane], b3 = red[3][lane];
    s.x += b1.x + b2.x + b3.x;
    s.y += b1.y + b2.y + b3.y;
    float2 self = __half22float2(*(const __half2*)(in + (size_t)c*128 + lane*2));
    float ox = dc*(dc*self.x + s.x);
    float oy = dc*(dc*self.y + s.y);
    if (act){
      ox = leaky(ox + bias[lane*2]);
      oy = leaky(oy + bias[lane*2+1]);
    }
    *(__half2*)(outp + (size_t)c*128 + lane*2) = __floats2half2_rn(ox, oy);
  }
  __syncthreads();   // red reuse across grid-stride iterations
}

// ------- fused attention (projected 64-dim), wave-per-node, 8-edge ILP, fdot2 --------
__device__ __forceinline__ void attn_unit(const GP& p, int u){
  const int n = NNODES;
  int w = threadIdx.x>>6, lane = threadIdx.x&63;
  int i = u*4 + w;
  int fo = lane*4;
  uint2 qtu = *(const uint2*)(p.qth + (size_t)i*256 + fo);
  h2v q0 = as_h2(qtu.x), q1 = as_h2(qtu.y);
  float4 wbv = *(const float4*)(p.wb + fo);
  uint2 hiu  = *(const uint2*)(p.h2h + (size_t)i*256 + fo);
  float2 hia = __half22float2(*(__half2*)&hiu.x);
  float2 hib = __half22float2(*(__half2*)&hiu.y);
  float pv = hia.x*wbv.x + hia.y*wbv.y + hib.x*wbv.z + hib.y*wbv.w;
  #pragma unroll
  for (int mm=32; mm; mm>>=1) pv += __shfl_xor(pv, mm, 64);
  float Ei = __expf(pv + p.s0p[0]);
  int e0 = p.ptrr[i], e1 = p.ptrr[i+1];
  float acc = 0.f, dsum = 0.f;
  for (int eb = e0; eb < e1; eb += 8){
    int m = e1 - eb; if (m > 8) m = 8;
    int j[8];
    #pragma unroll
    for (int u8=0;u8<8;u8++) j[u8] = p.csrd[(u8<m) ? eb+u8 : eb];
    uint2 hv[8]; float gv[8];
    #pragma unroll
    for (int u8=0;u8<8;u8++){
      hv[u8] = *(const uint2*)(p.h2h + (size_t)j[u8]*256 + fo);
      gv[u8] = __half2float(p.gh[(size_t)j[u8]*64 + lane]);
    }
    float d[8];
    #pragma unroll
    for (int u8=0;u8<8;u8++)
      d[u8] = __builtin_amdgcn_fdot2(q1, as_h2(hv[u8].y),
              __builtin_amdgcn_fdot2(q0, as_h2(hv[u8].x), 0.f, false), false);
    #pragma unroll
    for (int mm=32; mm; mm>>=1){
      #pragma unroll
      for (int u8=0;u8<8;u8++) d[u8] += __shfl_xor(d[u8], mm, 64);
    }
    #pragma unroll
    for (int u8=0;u8<8;u8++){
      if (u8 < m){
        float we = Ei * __expf(d[u8]);
        dsum += we;
        acc = fmaf(we - 1.f, gv[u8], acc);
      }
    }
  }
  float inv = 1.0f / ((float)(n - (e1 - e0)) + dsum);
  p.hw3h[(size_t)i*64 + lane] = __float2half((p.sw3[lane] + acc) * inv);
}

// ------- fused conv3 agg + bias + leaky + residual + LayerNorm + pool atomicMax ------
__device__ __forceinline__ void zp_unit(const GP& p, int c, char* smem){
  int t = threadIdx.x, w = t>>6, lane = t&63;
  float dc = p.dinv[c];
  float acc = 0.f;
  int e0 = p.ptrc[c], e1 = p.ptrc[c+1];
  for (int eb = e0 + w*4; eb < e1; eb += 16){
    int m = e1 - eb; if (m > 4) m = 4;
    int r[4];
    #pragma unroll
    for (int u=0;u<4;u++) r[u] = p.csrc[(u<m) ? eb+u : eb];
    float sc[4]; __half hval[4];
    #pragma unroll
    for (int u=0;u<4;u++){
      sc[u] = p.dinv[r[u]];
      hval[u] = p.hw3h[(size_t)r[u]*64 + lane];
    }
    #pragma unroll
    for (int u=0;u<4;u++)
      if (u < m) acc = fmaf(sc[u], __half2float(hval[u]), acc);
  }
  float (*red)[64] = (float(*)[64])smem;
  red[w][lane] = acc;
  __syncthreads();
  if (w == 0){
    acc = red[0][lane]+red[1][lane]+red[2][lane]+red[3][lane];
    float self = __half2float(p.hw3h[(size_t)c*64 + lane]);
    float v = leaky(dc*(dc*self + acc) + p.b3[lane]) + p.resid[(size_t)c*64 + lane];
    float s = v;
    #pragma unroll
    for (int mm=32; mm; mm>>=1) s += __shfl_xor(s, mm, 64);
    float mu = s * (1.0f/64.0f);
    float d = v - mu;
    float s2 = d*d;
    #pragma unroll
    for (int mm=32; mm; mm>>=1) s2 += __shfl_xor(s2, mm, 64);
    float zv = d * rsqrtf(s2*(1.0f/64.0f) + 1e-5f) * p.lng[lane] + p.lnb[lane];
    atomicMax(&p.poolpart[(c & 63)*64 + lane], fmap(zv));
  }
  __syncthreads();   // red reuse across grid-stride iterations
}

// ---------------- final: reduce poolpart buckets + 64x16 matvec ----------------
__device__ __forceinline__ void final_unit(const GP& p, char* smem){
  int t = threadIdx.x, f = t & 63, g = t >> 6;
  unsigned (*sm)[64] = (unsigned(*)[64])smem;
  float* pool = (float*)(smem + 1024);
  unsigned mu = 0u;
  for (int b = g; b < 64; b += 4) mu = max(mu, p.poolpart[b*64 + f]);
  sm[g][f] = mu;
  __syncthreads();
  if (g == 0)
    pool[f] = funmap(max(max(sm[0][f],sm[1][f]), max(sm[2][f],sm[3][f])));
  __syncthreads();
  if (t < 16){
    float a = p.bfv[t];
    #pragma unroll
    for (int ff=0; ff<64; ++ff) a = fmaf(pool[ff], p.Wf[ff*16 + t], a);
    p.out[t] = a;
  }
}

// ======================= single cooperative kernel: whole pipeline ===================
__global__ __launch_bounds__(256, 4) void k_coop(GP p){
  __shared__ __align__(16) char smem[SMEM_BYTES];
  cg::grid_group grid = cg::this_grid();
  const int G = gridDim.x;
  const int t = threadIdx.x;
  const int E = NEDGES, n = NNODES;
  _Float16 (*As)[40] = (_Float16(*)[40])smem;
  _Float16 (*Bs)[40] = (_Float16(*)[40])(smem + 5120);
  float* cs = (float*)(smem + 10240);

  // A: conversions / transposes / zeroing / small vectors
  for (int u = blockIdx.x; u < 1777; u += G) pre_unit(p, u, smem);
  grid.sync();
  // B: degrees + xw1 = x@W1 (transform-first conv1)
  for (int u = blockIdx.x; u < 1280; u += G){
    if (u < 1024){
      int e = u*256 + t;
      atomicAdd(&p.degc[p.ei[E+e]], 1);
      atomicAdd(&p.degr[p.ei[e]],   1);
    } else {
      int bb = u - 1024;
      gemm_tile(p.xh, p.W1t, nullptr, nullptr, p.xw1h, nullptr, 128, 128, 0, bb>>1, bb&1, As, Bs, nullptr);
    }
  }
  grid.sync();
  // C: scans (+dinv/cursors) co-running with Wqkt gemm + resid gemm
  for (int u = blockIdx.x; u < 146; u += G){
    if (u < 2) scan256(p, u, smem);
    else if (u < 18){
      int bb = u - 2;              // Wqkt = (Wq@Wk^T)^T = Wk@Wq^T
      gemm_tile(p.Wkh, p.Wqh, nullptr, nullptr, p.Wqkt, nullptr, 256, 256, 0, bb&3, bb>>2, As, Bs, nullptr);
    } else
      gemm_tile(p.xh, p.Wrt, p.br, p.resid, nullptr, nullptr, 128, 64, 0, u-18, 0, As, Bs, nullptr);
  }
  grid.sync();
  // D: CSR scatter (both directions)
  for (int u = blockIdx.x; u < 1024; u += G){
    int e = u*256 + t;
    int r = p.ei[e], c = p.ei[E+e];
    int p1 = atomicAdd(&p.curc[c],1); p.csrc[p1] = r;
    int p2 = atomicAdd(&p.curr[r],1); p.csrd[p2] = c;
  }
  grid.sync();
  // E: conv1 aggregate + bias + leaky -> h1
  for (int u = blockIdx.x; u < n; u += G)
    agg128_unit(p.xw1h, p.ptrc, p.csrc, p.dinv, p.h1h, p.b1, 1, u, smem);
  grid.sync();
  // F: conv2 aggregate (128-wide, pre-transform)
  for (int u = blockIdx.x; u < n; u += G)
    agg128_unit(p.h1h, p.ptrc, p.csrc, p.dinv, p.h1ah, nullptr, 0, u, smem);
  grid.sync();
  // G: conv2 transform: h2 = leaky(h1a@W2 + b2)
  for (int u = blockIdx.x; u < 512; u += G)
    gemm_tile(p.h1ah, p.W2t, p.b2, nullptr, p.h2h, nullptr, 128, 256, 1, u>>2, u&3, As, Bs, nullptr);
  grid.sync();
  // H: G = h2@W3 (+colsum) and qt = h2@Wqk + bqk
  for (int u = blockIdx.x; u < 640; u += G){
    if (u < 128) gemm_tile(p.h2h, p.W3t, nullptr, nullptr, p.gh, p.sw3, 256, 64, 0, u, 0, As, Bs, cs);
    else {
      int bb = u - 128;
      gemm_tile(p.h2h, p.Wqkt, p.bqk, nullptr, p.qth, nullptr, 256, 256, 0, bb>>2, bb&3, As, Bs, cs);
    }
  }
  grid.sync();
  // I: fused attention -> hw3h (projected 64-dim)
  for (int u = blockIdx.x; u < n/4; u += G) attn_unit(p, u);
  grid.sync();
  // J: conv3 agg + residual + LN + pool atomicMax
  for (int u = blockIdx.x; u < n; u += G) zp_unit(p, u, smem);
  grid.sync();
  // K: bucket reduce + matvec
  if (blockIdx.x == 0) final_unit(p, smem);
}

// ======================= fallback path: original 11-kernel pipeline ==================
__global__ __launch_bounds__(256) void kf_pre(GP p){
  __shared__ __align__(16) char smem[SMEM_BYTES];
  pre_unit(p, blockIdx.x, smem);
}
__global__ __launch_bounds__(256) void kf_dg(GP p){
  __shared__ __align__(16) char smem[SMEM_BYTES];
  _Float16 (*As)[40] = (_Float16(*)[40])smem;
  _Float16 (*Bs)[40] = (_Float16(*)[40])(smem + 5120);
  int b = blockIdx.x;
  if (b < 1024){
    int e = b*256 + threadIdx.x;
    atomicAdd(&p.degc[p.ei[NEDGES+e]], 1);
    atomicAdd(&p.degr[p.ei[e]],   1);
  } else {
    int bb = b - 1024;
    gemm_tile(p.xh, p.W1t, nullptr, nullptr, p.xw1h, nullptr, 128, 128, 0, bb>>1, bb&1, As, Bs, nullptr);
  }
}
__global__ __launch_bounds__(256) void kf_scan(GP p){
  __shared__ __align__(16) char smem[SMEM_BYTES];
  scan256(p, blockIdx.x, smem);
}
__global__ __launch_bounds__(256) void kf_mix1(GP p){
  __shared__ __align__(16) char smem[SMEM_BYTES];
  _Float16 (*As)[40] = (_Float16(*)[40])smem;
  _Float16 (*Bs)[40] = (_Float16(*)[40])(smem + 5120);
  int b = blockIdx.x;
  if (b < 1024){
    int e = b*256 + threadIdx.x;
    int r = p.ei[e], c = p.ei[NEDGES+e];
    int p1 = atomicAdd(&p.curc[c],1); p.csrc[p1] = r;
    int p2 = atomicAdd(&p.curr[r],1); p.csrd[p2] = c;
  } else if (b < 1040){
    int bb = b - 1024;
    gemm_tile(p.Wkh, p.Wqh, nullptr, nullptr, p.Wqkt, nullptr, 256, 256, 0, bb&3, bb>>2, As, Bs, nullptr);
  } else {
    gemm_tile(p.xh, p.Wrt, p.br, p.resid, nullptr, nullptr, 128, 64, 0, b-1040, 0, As, Bs, nullptr);
  }
}
__global__ __launch_bounds__(256) void kf_agg(GP p, int which){
  __shared__ __align__(16) char smem[SMEM_BYTES];
  if (which == 0)
    agg128_unit(p.xw1h, p.ptrc, p.csrc, p.dinv, p.h1h, p.b1, 1, blockIdx.x, smem);
  else
    agg128_unit(p.h1h, p.ptrc, p.csrc, p.dinv, p.h1ah, nullptr, 0, blockIdx.x, smem);
}
__global__ __launch_bounds__(256) void kf_gemm2(GP p){
  __shared__ __align__(16) char smem[SMEM_BYTES];
  _Float16 (*As)[40] = (_Float16(*)[40])smem;
  _Float16 (*Bs)[40] = (_Float16(*)[40])(smem + 5120);
  int b = blockIdx.x;
  gemm_tile(p.h1ah, p.W2t, p.b2, nullptr, p.h2h, nullptr, 128, 256, 1, b>>2, b&3, As, Bs, nullptr);
}
__global__ __launch_bounds__(256) void kf_mix2(GP p){
  __shared__ __align__(16) char smem[SMEM_BYTES];
  _Float16 (*As)[40] = (_Float16(*)[40])smem;
  _Float16 (*Bs)[40] = (_Float16(*)[40])(smem + 5120);
  float* cs = (float*)(smem + 10240);
  int b = blockIdx.x;
  if (b < 128) gemm_tile(p.h2h, p.W3t, nullptr, nullptr, p.gh, p.sw3, 256, 64, 0, b, 0, As, Bs, cs);
  else {
    int bb = b - 128;
    gemm_tile(p.h2h, p.Wqkt, p.bqk, nullptr, p.qth, nullptr, 256, 256, 0, bb>>2, bb&3, As, Bs, cs);
  }
}
__global__ __launch_bounds__(256) void kf_attn(GP p){ attn_unit(p, blockIdx.x); }
__global__ __launch_bounds__(256) void kf_zp(GP p){
  __shared__ __align__(16) char smem[SMEM_BYTES];
  zp_unit(p, blockIdx.x, smem);
}
__global__ __launch_bounds__(256) void kf_final(GP p){
  __shared__ __align__(16) char smem[SMEM_BYTES];
  final_unit(p, smem);
}

extern "C" void kernel_launch(void* const* d_in, const int* in_sizes, int n_in,
                              void* d_out, int out_size, void* d_ws, size_t ws_size,
                              hipStream_t stream){
  const int n = NNODES, E = NEDGES;
  char* ws = (char*)d_ws; size_t off = 0;
  auto alloc = [&](size_t bytes)->void*{
    void* pp = ws + off; off += (bytes + 255) & ~(size_t)255; return pp;
  };
  GP p;
  p.x   = (const float*)d_in[0];
  p.ei  = (const int*)d_in[1];
  p.W1  = (const float*)d_in[2];  p.b1 = (const float*)d_in[3];
  p.W2  = (const float*)d_in[4];  p.b2 = (const float*)d_in[5];
  p.W3  = (const float*)d_in[6];  p.b3 = (const float*)d_in[7];
  p.Wk  = (const float*)d_in[8];  p.bk = (const float*)d_in[9];
  p.Wq  = (const float*)d_in[10]; p.bq = (const float*)d_in[11];
  p.Wr  = (const float*)d_in[12]; p.br = (const float*)d_in[13];
  p.lng = (const float*)d_in[14]; p.lnb = (const float*)d_in[15];
  p.Wf  = (const float*)d_in[16]; p.bfv = (const float*)d_in[17];
  p.out = (float*)d_out;

  p.xh   = (__half*)alloc((size_t)n*128*2);
  p.xw1h = (__half*)alloc((size_t)n*128*2);
  p.h1h  = (__half*)alloc((size_t)n*128*2);
  p.h1ah = (__half*)alloc((size_t)n*128*2);
  p.h2h  = (__half*)alloc((size_t)n*256*2);
  p.qth  = (__half*)alloc((size_t)n*256*2);
  p.gh   = (__half*)alloc((size_t)n*64*2);
  p.hw3h = (__half*)alloc((size_t)n*64*2);
  p.resid= (float*)alloc((size_t)n*64*4);
  p.dinv = (float*)alloc((size_t)n*4);
  p.sw3  = (float*)alloc(64*4);
  p.Wqh  = (__half*)alloc(256*256*2);
  p.Wkh  = (__half*)alloc(256*256*2);
  p.Wqkt = (__half*)alloc(256*256*2);
  p.Wrt  = (__half*)alloc(128*64*2);
  p.W1t  = (__half*)alloc(128*128*2);
  p.W2t  = (__half*)alloc(128*256*2);
  p.W3t  = (__half*)alloc(256*64*2);
  p.bqk  = (float*)alloc(256*4);
  p.wb   = (float*)alloc(256*4);
  p.s0p  = (float*)alloc(4);
  p.degc = (int*)alloc((size_t)n*4);
  p.degr = (int*)alloc((size_t)n*4);
  p.ptrc = (int*)alloc((size_t)(n+1)*4);
  p.ptrr = (int*)alloc((size_t)(n+1)*4);
  p.curc = (int*)alloc((size_t)n*4);
  p.curr = (int*)alloc((size_t)n*4);
  p.csrc = (int*)alloc((size_t)E*4);
  p.csrd = (int*)alloc((size_t)E*4);
  p.poolpart = (unsigned*)alloc(64*64*4);

  // cooperative grid: co-residency-guaranteed size (occupancy query, host-only, no enqueue)
  static int coopGrid = 0;
  if (coopGrid == 0){
    int nb = 0;
    if (hipOccupancyMaxActiveBlocksPerMultiprocessor(&nb, k_coop, 256, 0) != hipSuccess || nb < 1)
      nb = 1;
    if (nb > 4) nb = 4;      // 4 blocks/CU is all the parallelism the phases need
    coopGrid = nb * 256;     // 256 CUs on MI355X
  }

  void* kargs[] = { (void*)&p };
  hipError_t cerr = hipLaunchCooperativeKernel(k_coop, dim3(coopGrid), dim3(256),
                                               kargs, 0, stream);
  if (cerr != hipSuccess){
    (void)hipGetLastError();   // clear sticky error, fall back to 11-kernel pipeline
    kf_pre  <<<dim3(1777), 256, 0, stream>>>(p);
    kf_dg   <<<dim3(1280), 256, 0, stream>>>(p);
    kf_scan <<<dim3(2),    256, 0, stream>>>(p);
    kf_mix1 <<<dim3(1168), 256, 0, stream>>>(p);
    kf_agg  <<<dim3(n),    256, 0, stream>>>(p, 0);
    kf_agg  <<<dim3(n),    256, 0, stream>>>(p, 1);
    kf_gemm2<<<dim3(512),  256, 0, stream>>>(p);
    kf_mix2 <<<dim3(640),  256, 0, stream>>>(p);
    kf_attn <<<dim3(n/4),  256, 0, stream>>>(p);
    kf_zp   <<<dim3(n),    256, 0, stream>>>(p);
    kf_final<<<dim3(1),    256, 0, stream>>>(p);
  }
}

// Round 3
// 263.290 us; speedup vs baseline: 3.6592x; 3.6592x over previous
//
#include <hip/hip_runtime.h>
#include <hip/hip_fp16.h>
#include <cstdint>
#include <cstddef>

#define NNODES 8192
#define NEDGES 262144
#define SMEM_BYTES 10496   // max over phases: gemm As(5120)+Bs(5120)+cs(256)

typedef _Float16 f16x8 __attribute__((ext_vector_type(8)));
typedef _Float16 h2v   __attribute__((ext_vector_type(2)));
typedef float    f32x4 __attribute__((ext_vector_type(4)));

__device__ __forceinline__ float leaky(float v){ return v > 0.f ? v : 0.01f*v; }

__device__ __forceinline__ unsigned fmap(float f){
  unsigned u = __float_as_uint(f);
  return (u & 0x80000000u) ? ~u : (u | 0x80000000u);
}
__device__ __forceinline__ float funmap(unsigned u){
  return (u & 0x80000000u) ? __uint_as_float(u & 0x7FFFFFFFu) : __uint_as_float(~u);
}
__device__ __forceinline__ h2v as_h2(unsigned u){
  union{ unsigned x; h2v h; } c; c.x = u; return c.h;
}

// ---------------- all device pointers in one struct (single kernel arg) ----------
struct GP {
  const float *x; const int *ei;
  const float *W1,*b1,*W2,*b2,*W3,*b3,*Wk,*bk,*Wq,*bq,*Wr,*br,*lng,*lnb,*Wf,*bfv;
  float* out;
  __half *xh,*xw1h,*h1h,*h1ah,*h2h,*qth,*gh,*hw3h;
  float *resid,*dinv,*sw3;
  __half *Wqh,*Wkh,*Wqkt,*Wrt,*W1t,*W2t,*W3t;
  float *bqk,*wb,*s0p;
  int *degc,*degr,*ptrc,*ptrr,*curc,*curr,*csrc,*csrd;
  unsigned* poolpart;
};

// ================= pre unit: conversions / transposes / zeroing / small vectors ====
// [0,1024): x->xh vec4 | [1024,1088): Wq | [1088,1152): Wk | [1152,1184): Wrt
// [1184,1248): W1t | [1248,1376): W2t | [1376,1440): W3t
// [1440,1504): zero degc/degr | [1504,1520): zero poolpart | 1520: zero sw3
// [1521,1777): smallvec (coalesced): bqk[c]=Wk_row_c.bq, wb[c]=Wq_row_c.bk; c0 adds s0
__device__ __forceinline__ void pre_unit(const GP& p, int b, char* smem){
  int t = threadIdx.x;
  if (b < 1024){
    int base = (b*256 + t)*4;
    float4 xv = *(const float4*)(p.x + base);
    uint2 o;
    *(__half2*)&o.x = __floats2half2_rn(xv.x, xv.y);
    *(__half2*)&o.y = __floats2half2_rn(xv.z, xv.w);
    *(uint2*)(p.xh + base) = o;
  } else if (b < 1088){
    int base = ((b-1024)*256 + t)*4;
    float4 v = *(const float4*)(p.Wq + base);
    uint2 o;
    *(__half2*)&o.x = __floats2half2_rn(v.x, v.y);
    *(__half2*)&o.y = __floats2half2_rn(v.z, v.w);
    *(uint2*)(p.Wqh + base) = o;
  } else if (b < 1152){
    int base = ((b-1088)*256 + t)*4;
    float4 v = *(const float4*)(p.Wk + base);
    uint2 o;
    *(__half2*)&o.x = __floats2half2_rn(v.x, v.y);
    *(__half2*)&o.y = __floats2half2_rn(v.z, v.w);
    *(uint2*)(p.Wkh + base) = o;
  } else if (b < 1184){         // Wr[128][64] -> Wrt[64][128]
    int idx = (b-1152)*256 + t;
    int nn = idx >> 7, k = idx & 127;
    p.Wrt[idx] = __float2half(p.Wr[k*64 + nn]);
  } else if (b < 1248){         // W1[128][128] -> W1t[128][128]
    int idx = (b-1184)*256 + t;
    int nn = idx >> 7, k = idx & 127;
    p.W1t[idx] = __float2half(p.W1[k*128 + nn]);
  } else if (b < 1376){         // W2[128][256] -> W2t[256][128]
    int idx = (b-1248)*256 + t;
    int nn = idx >> 7, k = idx & 127;
    p.W2t[idx] = __float2half(p.W2[k*256 + nn]);
  } else if (b < 1440){         // W3[256][64] -> W3t[64][256]
    int idx = (b-1376)*256 + t;
    int nn = idx >> 8, k = idx & 255;
    p.W3t[idx] = __float2half(p.W3[k*64 + nn]);
  } else if (b < 1504){
    int idx = (b-1440)*256 + t;
    if (idx < 8192) p.degc[idx]=0; else p.degr[idx-8192]=0;
  } else if (b < 1520){
    p.poolpart[(b-1504)*256 + t] = 0u;
  } else if (b == 1520){
    if (t < 64) p.sw3[t]=0.f;
  } else {                      // smallvec: coalesced row read + block reduce
    int c = b - 1521;
    float* ra = (float*)smem; float* rb = ra + 256; float* rc = rb + 256;
    ra[t] = p.Wk[c*256 + t] * p.bq[t];
    rb[t] = p.Wq[c*256 + t] * p.bk[t];
    if (c == 0) rc[t] = p.bq[t]*p.bk[t];
    __syncthreads();
    for (int off=128; off; off>>=1){
      if (t < off){
        ra[t] += ra[t+off];
        rb[t] += rb[t+off];
        if (c == 0) rc[t] += rc[t+off];
      }
      __syncthreads();
    }
    if (t == 0){
      p.bqk[c] = ra[0];
      p.wb[c]  = rb[0];
      if (c == 0) p.s0p[0] = rc[0];
    }
  }
}

// ---------------- MFMA GEMM tile (device): C64x64 = A[.,K] @ Bt[.,K]^T ----------------
__device__ __forceinline__ void gemm_tile(const __half* __restrict__ A,
    const __half* __restrict__ Bt, const float* __restrict__ bias,
    float* __restrict__ Cf, __half* __restrict__ Ch, float* __restrict__ csum,
    int K, int N, int act, int bx, int by,
    _Float16 (*As)[40], _Float16 (*Bs)[40], float* cs){
  int t = threadIdx.x, w = t>>6, lane = t&63;
  int m0 = bx*64, n0 = by*64;
  int quad = lane>>4, l15 = lane&15;
  int srow = t>>2, soff = (t&3)*8;
  f32x4 acc0 = {0.f,0.f,0.f,0.f}, acc1 = acc0, acc2 = acc0, acc3 = acc0;
  for (int k0 = 0; k0 < K; k0 += 32){
    *(uint4*)&As[srow][soff] = *(const uint4*)(A  + (size_t)(m0+srow)*K + k0 + soff);
    *(uint4*)&Bs[srow][soff] = *(const uint4*)(Bt + (size_t)(n0+srow)*K + k0 + soff);
    __syncthreads();
    f16x8 af = *(const f16x8*)&As[w*16 + l15][quad*8];
    f16x8 b0 = *(const f16x8*)&Bs[ 0 + l15][quad*8];
    f16x8 b1 = *(const f16x8*)&Bs[16 + l15][quad*8];
    f16x8 b2 = *(const f16x8*)&Bs[32 + l15][quad*8];
    f16x8 b3 = *(const f16x8*)&Bs[48 + l15][quad*8];
    acc0 = __builtin_amdgcn_mfma_f32_16x16x32_f16(af, b0, acc0, 0,0,0);
    acc1 = __builtin_amdgcn_mfma_f32_16x16x32_f16(af, b1, acc1, 0,0,0);
    acc2 = __builtin_amdgcn_mfma_f32_16x16x32_f16(af, b2, acc2, 0,0,0);
    acc3 = __builtin_amdgcn_mfma_f32_16x16x32_f16(af, b3, acc3, 0,0,0);
    __syncthreads();
  }
  f32x4 accs[4] = {acc0, acc1, acc2, acc3};
  if (csum){
    if (t < 64) cs[t] = 0.f;
    __syncthreads();
    #pragma unroll
    for (int nt=0; nt<4; ++nt){
      float pp = accs[nt][0]+accs[nt][1]+accs[nt][2]+accs[nt][3];
      atomicAdd(&cs[nt*16 + l15], pp);
    }
    __syncthreads();
    if (t < 64) atomicAdd(&csum[n0 + t], cs[t]);
  }
  #pragma unroll
  for (int nt=0; nt<4; ++nt){
    int col = n0 + nt*16 + l15;
    float bv = bias ? bias[col] : 0.f;
    #pragma unroll
    for (int r=0;r<4;r++){
      int row = m0 + w*16 + quad*4 + r;
      float v = accs[nt][r] + bv;
      if (act) v = leaky(v);
      if (Cf) Cf[(size_t)row*N + col] = v;
      if (Ch) Ch[(size_t)row*N + col] = __float2half(v);
    }
  }
}

// -------- 256-thread exclusive scan + prep (side 0: col w/ dinv; side 1: row) --------
// 32 nodes per thread, two passes over deg (L2-hot); wave scan + 4-wave LDS combine
__device__ __forceinline__ void scan256(const GP& p, int side, char* smem){
  const int n = NNODES;
  const int* deg = side ? p.degr : p.degc;
  int* ptr = side ? p.ptrr : p.ptrc;
  int* cur = side ? p.curr : p.curc;
  int t = threadIdx.x, lane = t & 63, wid = t >> 6;
  int base = t*32;
  int s = 0;
  #pragma unroll 4
  for (int q=0;q<32;q++) s += deg[base+q];
  int sc = s;
  #pragma unroll
  for (int o=1;o<64;o<<=1){ int v = __shfl_up(sc, o, 64); if (lane >= o) sc += v; }
  int* wsum = (int*)smem;
  if (lane==63) wsum[wid] = sc;
  __syncthreads();
  int add = 0;
  #pragma unroll
  for (int k=0;k<3;k++) if (k < wid) add += wsum[k];
  int run = add + sc - s;
  for (int q=0;q<32;q++){
    int d = deg[base+q];
    ptr[base+q] = run;
    cur[base+q] = run;
    if (!side) p.dinv[base+q] = rsqrtf((float)(d+1));
    run += d;
  }
  if (t==255) ptr[n] = run;
}

// -------- GCN aggregation, F=128: 4 waves split edges, ILP-4, optional bias+leaky ----
__device__ __forceinline__ void agg128_unit(const __half* __restrict__ in,
    const int* __restrict__ ptr, const int* __restrict__ src,
    const float* __restrict__ dinv, __half* __restrict__ outp,
    const float* __restrict__ bias, int act, int c, char* smem){
  int t = threadIdx.x, w = t>>6, lane = t&63;
  float dc = dinv[c];
  float2 acc = make_float2(0.f, 0.f);
  int e0 = ptr[c], e1 = ptr[c+1];
  for (int eb = e0 + w*4; eb < e1; eb += 16){
    int m = e1 - eb; if (m > 4) m = 4;
    int r[4];
    #pragma unroll
    for (int u=0;u<4;u++) r[u] = src[(u<m) ? eb+u : eb];
    float sc[4]; __half2 hv[4];
    #pragma unroll
    for (int u=0;u<4;u++){
      sc[u] = dinv[r[u]];
      hv[u] = *(const __half2*)(in + (size_t)r[u]*128 + lane*2);
    }
    #pragma unroll
    for (int u=0;u<4;u++){
      if (u < m){
        float2 h = __half22float2(hv[u]);
        acc.x = fmaf(sc[u], h.x, acc.x);
        acc.y = fmaf(sc[u], h.y, acc.y);
      }
    }
  }
  float2 (*red)[64] = (float2(*)[64])smem;
  red[w][lane] = acc;
  __syncthreads();
  if (w == 0){
    float2 s = red[0][lane];
    float2 b1 = red[1][lane], b2 = red[2][lane], b3 = red[3][lane];
    s.x += b1.x + b2.x + b3.x;
    s.y += b1.y + b2.y + b3.y;
    float2 self = __half22float2(*(const __half2*)(in + (size_t)c*128 + lane*2));
    float ox = dc*(dc*self.x + s.x);
    float oy = dc*(dc*self.y + s.y);
    if (act){
      ox = leaky(ox + bias[lane*2]);
      oy = leaky(oy + bias[lane*2+1]);
    }
    *(__half2*)(outp + (size_t)c*128 + lane*2) = __floats2half2_rn(ox, oy);
  }
}

// ------- fused attention (projected 64-dim), wave-per-node, 8-edge ILP, fdot2 --------
__device__ __forceinline__ void attn_unit(const GP& p, int u){
  const int n = NNODES;
  int w = threadIdx.x>>6, lane = threadIdx.x&63;
  int i = u*4 + w;
  int fo = lane*4;
  uint2 qtu = *(const uint2*)(p.qth + (size_t)i*256 + fo);
  h2v q0 = as_h2(qtu.x), q1 = as_h2(qtu.y);
  float4 wbv = *(const float4*)(p.wb + fo);
  uint2 hiu  = *(const uint2*)(p.h2h + (size_t)i*256 + fo);
  float2 hia = __half22float2(*(__half2*)&hiu.x);
  float2 hib = __half22float2(*(__half2*)&hiu.y);
  float pv = hia.x*wbv.x + hia.y*wbv.y + hib.x*wbv.z + hib.y*wbv.w;
  #pragma unroll
  for (int mm=32; mm; mm>>=1) pv += __shfl_xor(pv, mm, 64);
  float Ei = __expf(pv + p.s0p[0]);
  int e0 = p.ptrr[i], e1 = p.ptrr[i+1];
  float acc = 0.f, dsum = 0.f;
  for (int eb = e0; eb < e1; eb += 8){
    int m = e1 - eb; if (m > 8) m = 8;
    int j[8];
    #pragma unroll
    for (int u8=0;u8<8;u8++) j[u8] = p.csrd[(u8<m) ? eb+u8 : eb];
    uint2 hv[8]; float gv[8];
    #pragma unroll
    for (int u8=0;u8<8;u8++){
      hv[u8] = *(const uint2*)(p.h2h + (size_t)j[u8]*256 + fo);
      gv[u8] = __half2float(p.gh[(size_t)j[u8]*64 + lane]);
    }
    float d[8];
    #pragma unroll
    for (int u8=0;u8<8;u8++)
      d[u8] = __builtin_amdgcn_fdot2(q1, as_h2(hv[u8].y),
              __builtin_amdgcn_fdot2(q0, as_h2(hv[u8].x), 0.f, false), false);
    #pragma unroll
    for (int mm=32; mm; mm>>=1){
      #pragma unroll
      for (int u8=0;u8<8;u8++) d[u8] += __shfl_xor(d[u8], mm, 64);
    }
    #pragma unroll
    for (int u8=0;u8<8;u8++){
      if (u8 < m){
        float we = Ei * __expf(d[u8]);
        dsum += we;
        acc = fmaf(we - 1.f, gv[u8], acc);
      }
    }
  }
  float inv = 1.0f / ((float)(n - (e1 - e0)) + dsum);
  p.hw3h[(size_t)i*64 + lane] = __float2half((p.sw3[lane] + acc) * inv);
}

// ------- fused conv3 agg + bias + leaky + residual + LayerNorm + pool atomicMax ------
__device__ __forceinline__ void zp_unit(const GP& p, int c, char* smem){
  int t = threadIdx.x, w = t>>6, lane = t&63;
  float dc = p.dinv[c];
  float acc = 0.f;
  int e0 = p.ptrc[c], e1 = p.ptrc[c+1];
  for (int eb = e0 + w*4; eb < e1; eb += 16){
    int m = e1 - eb; if (m > 4) m = 4;
    int r[4];
    #pragma unroll
    for (int u=0;u<4;u++) r[u] = p.csrc[(u<m) ? eb+u : eb];
    float sc[4]; __half hval[4];
    #pragma unroll
    for (int u=0;u<4;u++){
      sc[u] = p.dinv[r[u]];
      hval[u] = p.hw3h[(size_t)r[u]*64 + lane];
    }
    #pragma unroll
    for (int u=0;u<4;u++)
      if (u < m) acc = fmaf(sc[u], __half2float(hval[u]), acc);
  }
  float (*red)[64] = (float(*)[64])smem;
  red[w][lane] = acc;
  __syncthreads();
  if (w == 0){
    acc = red[0][lane]+red[1][lane]+red[2][lane]+red[3][lane];
    float self = __half2float(p.hw3h[(size_t)c*64 + lane]);
    float v = leaky(dc*(dc*self + acc) + p.b3[lane]) + p.resid[(size_t)c*64 + lane];
    float s = v;
    #pragma unroll
    for (int mm=32; mm; mm>>=1) s += __shfl_xor(s, mm, 64);
    float mu = s * (1.0f/64.0f);
    float d = v - mu;
    float s2 = d*d;
    #pragma unroll
    for (int mm=32; mm; mm>>=1) s2 += __shfl_xor(s2, mm, 64);
    float zv = d * rsqrtf(s2*(1.0f/64.0f) + 1e-5f) * p.lng[lane] + p.lnb[lane];
    atomicMax(&p.poolpart[(c & 63)*64 + lane], fmap(zv));
  }
}

// ---------------- final: reduce poolpart buckets + 64x16 matvec ----------------
__device__ __forceinline__ void final_unit(const GP& p, char* smem){
  int t = threadIdx.x, f = t & 63, g = t >> 6;
  unsigned (*sm)[64] = (unsigned(*)[64])smem;
  float* pool = (float*)(smem + 1024);
  unsigned mu = 0u;
  for (int b = g; b < 64; b += 4) mu = max(mu, p.poolpart[b*64 + f]);
  sm[g][f] = mu;
  __syncthreads();
  if (g == 0)
    pool[f] = funmap(max(max(sm[0][f],sm[1][f]), max(sm[2][f],sm[3][f])));
  __syncthreads();
  if (t < 16){
    float a = p.bfv[t];
    #pragma unroll
    for (int ff=0; ff<64; ++ff) a = fmaf(pool[ff], p.Wf[ff*16 + t], a);
    p.out[t] = a;
  }
}

// ======================= kernels (one launch per pipeline stage) =====================
__global__ __launch_bounds__(256) void k_pre(GP p){
  __shared__ __align__(16) char smem[SMEM_BYTES];
  pre_unit(p, blockIdx.x, smem);
}

// degrees + xw1 = x@W1 (transform-first conv1, overlapped)
__global__ __launch_bounds__(256) void k_dg(GP p){
  __shared__ __align__(16) char smem[SMEM_BYTES];
  _Float16 (*As)[40] = (_Float16(*)[40])smem;
  _Float16 (*Bs)[40] = (_Float16(*)[40])(smem + 5120);
  int b = blockIdx.x;
  if (b < 1024){
    int e = b*256 + threadIdx.x;
    atomicAdd(&p.degc[p.ei[NEDGES+e]], 1);
    atomicAdd(&p.degr[p.ei[e]],   1);
  } else {
    int bb = b - 1024;
    gemm_tile(p.xh, p.W1t, nullptr, nullptr, p.xw1h, nullptr, 128, 128, 0, bb>>1, bb&1, As, Bs, nullptr);
  }
}

// scans (2 blocks) co-running with Wqkt gemm (16) + resid gemm (128) — fills the bubble
__global__ __launch_bounds__(256) void k_scan2(GP p){
  __shared__ __align__(16) char smem[SMEM_BYTES];
  _Float16 (*As)[40] = (_Float16(*)[40])smem;
  _Float16 (*Bs)[40] = (_Float16(*)[40])(smem + 5120);
  int b = blockIdx.x;
  if (b < 2) scan256(p, b, smem);
  else if (b < 18){
    int bb = b - 2;                // Wqkt = (Wq@Wk^T)^T = Wk@Wq^T
    gemm_tile(p.Wkh, p.Wqh, nullptr, nullptr, p.Wqkt, nullptr, 256, 256, 0, bb&3, bb>>2, As, Bs, nullptr);
  } else
    gemm_tile(p.xh, p.Wrt, p.br, p.resid, nullptr, nullptr, 128, 64, 0, b-18, 0, As, Bs, nullptr);
}

// pure CSR scatter (both directions)
__global__ __launch_bounds__(256) void k_scat(GP p){
  int e = blockIdx.x*256 + threadIdx.x;
  int r = p.ei[e], c = p.ei[NEDGES+e];
  int p1 = atomicAdd(&p.curc[c],1); p.csrc[p1] = r;
  int p2 = atomicAdd(&p.curr[r],1); p.csrd[p2] = c;
}

__global__ __launch_bounds__(256) void k_agg(GP p, int which){
  __shared__ __align__(16) char smem[SMEM_BYTES];
  if (which == 0)
    agg128_unit(p.xw1h, p.ptrc, p.csrc, p.dinv, p.h1h, p.b1, 1, blockIdx.x, smem);
  else
    agg128_unit(p.h1h, p.ptrc, p.csrc, p.dinv, p.h1ah, nullptr, 0, blockIdx.x, smem);
}

// conv2 transform: h2 = leaky(h1a@W2 + b2)
__global__ __launch_bounds__(256) void k_gemm2(GP p){
  __shared__ __align__(16) char smem[SMEM_BYTES];
  _Float16 (*As)[40] = (_Float16(*)[40])smem;
  _Float16 (*Bs)[40] = (_Float16(*)[40])(smem + 5120);
  int b = blockIdx.x;
  gemm_tile(p.h1ah, p.W2t, p.b2, nullptr, p.h2h, nullptr, 128, 256, 1, b>>2, b&3, As, Bs, nullptr);
}

// G = h2@W3 (+colsum) and qt = h2@Wqk + bqk
__global__ __launch_bounds__(256) void k_mix2(GP p){
  __shared__ __align__(16) char smem[SMEM_BYTES];
  _Float16 (*As)[40] = (_Float16(*)[40])smem;
  _Float16 (*Bs)[40] = (_Float16(*)[40])(smem + 5120);
  float* cs = (float*)(smem + 10240);
  int b = blockIdx.x;
  if (b < 128) gemm_tile(p.h2h, p.W3t, nullptr, nullptr, p.gh, p.sw3, 256, 64, 0, b, 0, As, Bs, cs);
  else {
    int bb = b - 128;
    gemm_tile(p.h2h, p.Wqkt, p.bqk, nullptr, p.qth, nullptr, 256, 256, 0, bb>>2, bb&3, As, Bs, cs);
  }
}

__global__ __launch_bounds__(256) void k_attn(GP p){ attn_unit(p, blockIdx.x); }

__global__ __launch_bounds__(256) void k_zp(GP p){
  __shared__ __align__(16) char smem[SMEM_BYTES];
  zp_unit(p, blockIdx.x, smem);
}

__global__ __launch_bounds__(256) void k_final(GP p){
  __shared__ __align__(16) char smem[SMEM_BYTES];
  final_unit(p, smem);
}

extern "C" void kernel_launch(void* const* d_in, const int* in_sizes, int n_in,
                              void* d_out, int out_size, void* d_ws, size_t ws_size,
                              hipStream_t stream){
  const int n = NNODES, E = NEDGES;
  char* ws = (char*)d_ws; size_t off = 0;
  auto alloc = [&](size_t bytes)->void*{
    void* pp = ws + off; off += (bytes + 255) & ~(size_t)255; return pp;
  };
  GP p;
  p.x   = (const float*)d_in[0];
  p.ei  = (const int*)d_in[1];
  p.W1  = (const float*)d_in[2];  p.b1 = (const float*)d_in[3];
  p.W2  = (const float*)d_in[4];  p.b2 = (const float*)d_in[5];
  p.W3  = (const float*)d_in[6];  p.b3 = (const float*)d_in[7];
  p.Wk  = (const float*)d_in[8];  p.bk = (const float*)d_in[9];
  p.Wq  = (const float*)d_in[10]; p.bq = (const float*)d_in[11];
  p.Wr  = (const float*)d_in[12]; p.br = (const float*)d_in[13];
  p.lng = (const float*)d_in[14]; p.lnb = (const float*)d_in[15];
  p.Wf  = (const float*)d_in[16]; p.bfv = (const float*)d_in[17];
  p.out = (float*)d_out;

  p.xh   = (__half*)alloc((size_t)n*128*2);
  p.xw1h = (__half*)alloc((size_t)n*128*2);
  p.h1h  = (__half*)alloc((size_t)n*128*2);
  p.h1ah = (__half*)alloc((size_t)n*128*2);
  p.h2h  = (__half*)alloc((size_t)n*256*2);
  p.qth  = (__half*)alloc((size_t)n*256*2);
  p.gh   = (__half*)alloc((size_t)n*64*2);
  p.hw3h = (__half*)alloc((size_t)n*64*2);
  p.resid= (float*)alloc((size_t)n*64*4);
  p.dinv = (float*)alloc((size_t)n*4);
  p.sw3  = (float*)alloc(64*4);
  p.Wqh  = (__half*)alloc(256*256*2);
  p.Wkh  = (__half*)alloc(256*256*2);
  p.Wqkt = (__half*)alloc(256*256*2);
  p.Wrt  = (__half*)alloc(128*64*2);
  p.W1t  = (__half*)alloc(128*128*2);
  p.W2t  = (__half*)alloc(128*256*2);
  p.W3t  = (__half*)alloc(256*64*2);
  p.bqk  = (float*)alloc(256*4);
  p.wb   = (float*)alloc(256*4);
  p.s0p  = (float*)alloc(4);
  p.degc = (int*)alloc((size_t)n*4);
  p.degr = (int*)alloc((size_t)n*4);
  p.ptrc = (int*)alloc((size_t)(n+1)*4);
  p.ptrr = (int*)alloc((size_t)(n+1)*4);
  p.curc = (int*)alloc((size_t)n*4);
  p.curr = (int*)alloc((size_t)n*4);
  p.csrc = (int*)alloc((size_t)E*4);
  p.csrd = (int*)alloc((size_t)E*4);
  p.poolpart = (unsigned*)alloc(64*64*4);

  k_pre  <<<dim3(1777), 256, 0, stream>>>(p);   // conversions/transposes/zero/smallvec
  k_dg   <<<dim3(1280), 256, 0, stream>>>(p);   // degrees + xw1 gemm
  k_scan2<<<dim3(146),  256, 0, stream>>>(p);   // scans + Wqkt gemm + resid gemm
  k_scat <<<dim3(1024), 256, 0, stream>>>(p);   // CSR scatter
  k_agg  <<<dim3(n),    256, 0, stream>>>(p, 0);// conv1 aggregate + bias + leaky
  k_agg  <<<dim3(n),    256, 0, stream>>>(p, 1);// conv2 aggregate
  k_gemm2<<<dim3(512),  256, 0, stream>>>(p);   // h2 = leaky(h1a@W2+b2)
  k_mix2 <<<dim3(640),  256, 0, stream>>>(p);   // G=h2@W3 (+colsum), qt=h2@Wqk+bqk
  k_attn <<<dim3(n/4),  256, 0, stream>>>(p);   // fused attention
  k_zp   <<<dim3(n),    256, 0, stream>>>(p);   // conv3 agg+resid+LN+pool
  k_final<<<dim3(1),    256, 0, stream>>>(p);   // bucket reduce + matvec
}

// Round 4
// 224.426 us; speedup vs baseline: 4.2928x; 1.1732x over previous
//
#include <hip/hip_runtime.h>
#include <hip/hip_fp16.h>
#include <cstdint>
#include <cstddef>

#define NNODES 8192
#define NEDGES 262144
#define MAXDEG 96          // mean degree 32, sigma 5.7 -> +11 sigma headroom
#define SMEM_BYTES 10496   // max over phases: gemm As(5120)+Bs(5120)+cs(256)

typedef _Float16 f16x8 __attribute__((ext_vector_type(8)));
typedef _Float16 h2v   __attribute__((ext_vector_type(2)));
typedef float    f32x4 __attribute__((ext_vector_type(4)));

__device__ __forceinline__ float leaky(float v){ return v > 0.f ? v : 0.01f*v; }

__device__ __forceinline__ unsigned fmap(float f){
  unsigned u = __float_as_uint(f);
  return (u & 0x80000000u) ? ~u : (u | 0x80000000u);
}
__device__ __forceinline__ float funmap(unsigned u){
  return (u & 0x80000000u) ? __uint_as_float(u & 0x7FFFFFFFu) : __uint_as_float(~u);
}
__device__ __forceinline__ h2v as_h2(unsigned u){
  union{ unsigned x; h2v h; } c; c.x = u; return c.h;
}

// ---------------- all device pointers in one struct (single kernel arg) ----------
struct GP {
  const float *x; const int *ei;
  const float *W1,*b1,*W2,*b2,*W3,*b3,*Wk,*bk,*Wq,*bq,*Wr,*br,*lng,*lnb,*Wf,*bfv;
  float* out;
  __half *xh,*xw1h,*h1h,*h1ah,*h2h,*qth,*gh,*hw3h;
  float *resid,*sw3;
  __half *Wqh,*Wkh,*Wqkt,*Wrt,*W1t,*W2t,*W3t;
  float *bqk,*wb,*s0p;
  int *degc,*degr,*csrc,*csrd;
  unsigned* poolpart;
};

// ================= pre unit: conversions / transposes / zeroing / small vectors ====
// [0,1024): x->xh vec4 | [1024,1088): Wq | [1088,1152): Wk | [1152,1184): Wrt
// [1184,1248): W1t | [1248,1376): W2t | [1376,1440): W3t
// [1440,1504): zero degc/degr | [1504,1520): zero poolpart | 1520: zero sw3
// [1521,1777): smallvec (coalesced): bqk[c]=Wk_row_c.bq, wb[c]=Wq_row_c.bk; c0 adds s0
__device__ __forceinline__ void pre_unit(const GP& p, int b, char* smem){
  int t = threadIdx.x;
  if (b < 1024){
    int base = (b*256 + t)*4;
    float4 xv = *(const float4*)(p.x + base);
    uint2 o;
    *(__half2*)&o.x = __floats2half2_rn(xv.x, xv.y);
    *(__half2*)&o.y = __floats2half2_rn(xv.z, xv.w);
    *(uint2*)(p.xh + base) = o;
  } else if (b < 1088){
    int base = ((b-1024)*256 + t)*4;
    float4 v = *(const float4*)(p.Wq + base);
    uint2 o;
    *(__half2*)&o.x = __floats2half2_rn(v.x, v.y);
    *(__half2*)&o.y = __floats2half2_rn(v.z, v.w);
    *(uint2*)(p.Wqh + base) = o;
  } else if (b < 1152){
    int base = ((b-1088)*256 + t)*4;
    float4 v = *(const float4*)(p.Wk + base);
    uint2 o;
    *(__half2*)&o.x = __floats2half2_rn(v.x, v.y);
    *(__half2*)&o.y = __floats2half2_rn(v.z, v.w);
    *(uint2*)(p.Wkh + base) = o;
  } else if (b < 1184){         // Wr[128][64] -> Wrt[64][128]
    int idx = (b-1152)*256 + t;
    int nn = idx >> 7, k = idx & 127;
    p.Wrt[idx] = __float2half(p.Wr[k*64 + nn]);
  } else if (b < 1248){         // W1[128][128] -> W1t[128][128]
    int idx = (b-1184)*256 + t;
    int nn = idx >> 7, k = idx & 127;
    p.W1t[idx] = __float2half(p.W1[k*128 + nn]);
  } else if (b < 1376){         // W2[128][256] -> W2t[256][128]
    int idx = (b-1248)*256 + t;
    int nn = idx >> 7, k = idx & 127;
    p.W2t[idx] = __float2half(p.W2[k*256 + nn]);
  } else if (b < 1440){         // W3[256][64] -> W3t[64][256]
    int idx = (b-1376)*256 + t;
    int nn = idx >> 8, k = idx & 255;
    p.W3t[idx] = __float2half(p.W3[k*64 + nn]);
  } else if (b < 1504){
    int idx = (b-1440)*256 + t;
    if (idx < 8192) p.degc[idx]=0; else p.degr[idx-8192]=0;
  } else if (b < 1520){
    p.poolpart[(b-1504)*256 + t] = 0u;
  } else if (b == 1520){
    if (t < 64) p.sw3[t]=0.f;
  } else {                      // smallvec: coalesced row read + block reduce
    int c = b - 1521;
    float* ra = (float*)smem; float* rb = ra + 256; float* rc = rb + 256;
    ra[t] = p.Wk[c*256 + t] * p.bq[t];
    rb[t] = p.Wq[c*256 + t] * p.bk[t];
    if (c == 0) rc[t] = p.bq[t]*p.bk[t];
    __syncthreads();
    for (int off=128; off; off>>=1){
      if (t < off){
        ra[t] += ra[t+off];
        rb[t] += rb[t+off];
        if (c == 0) rc[t] += rc[t+off];
      }
      __syncthreads();
    }
    if (t == 0){
      p.bqk[c] = ra[0];
      p.wb[c]  = rb[0];
      if (c == 0) p.s0p[0] = rc[0];
    }
  }
}

// ---------------- MFMA GEMM tile (device): C64x64 = A[.,K] @ Bt[.,K]^T ----------------
__device__ __forceinline__ void gemm_tile(const __half* __restrict__ A,
    const __half* __restrict__ Bt, const float* __restrict__ bias,
    float* __restrict__ Cf, __half* __restrict__ Ch, float* __restrict__ csum,
    int K, int N, int act, int bx, int by,
    _Float16 (*As)[40], _Float16 (*Bs)[40], float* cs){
  int t = threadIdx.x, w = t>>6, lane = t&63;
  int m0 = bx*64, n0 = by*64;
  int quad = lane>>4, l15 = lane&15;
  int srow = t>>2, soff = (t&3)*8;
  f32x4 acc0 = {0.f,0.f,0.f,0.f}, acc1 = acc0, acc2 = acc0, acc3 = acc0;
  for (int k0 = 0; k0 < K; k0 += 32){
    *(uint4*)&As[srow][soff] = *(const uint4*)(A  + (size_t)(m0+srow)*K + k0 + soff);
    *(uint4*)&Bs[srow][soff] = *(const uint4*)(Bt + (size_t)(n0+srow)*K + k0 + soff);
    __syncthreads();
    f16x8 af = *(const f16x8*)&As[w*16 + l15][quad*8];
    f16x8 b0 = *(const f16x8*)&Bs[ 0 + l15][quad*8];
    f16x8 b1 = *(const f16x8*)&Bs[16 + l15][quad*8];
    f16x8 b2 = *(const f16x8*)&Bs[32 + l15][quad*8];
    f16x8 b3 = *(const f16x8*)&Bs[48 + l15][quad*8];
    acc0 = __builtin_amdgcn_mfma_f32_16x16x32_f16(af, b0, acc0, 0,0,0);
    acc1 = __builtin_amdgcn_mfma_f32_16x16x32_f16(af, b1, acc1, 0,0,0);
    acc2 = __builtin_amdgcn_mfma_f32_16x16x32_f16(af, b2, acc2, 0,0,0);
    acc3 = __builtin_amdgcn_mfma_f32_16x16x32_f16(af, b3, acc3, 0,0,0);
    __syncthreads();
  }
  f32x4 accs[4] = {acc0, acc1, acc2, acc3};
  if (csum){
    if (t < 64) cs[t] = 0.f;
    __syncthreads();
    #pragma unroll
    for (int nt=0; nt<4; ++nt){
      float pp = accs[nt][0]+accs[nt][1]+accs[nt][2]+accs[nt][3];
      atomicAdd(&cs[nt*16 + l15], pp);
    }
    __syncthreads();
    if (t < 64) atomicAdd(&csum[n0 + t], cs[t]);
  }
  #pragma unroll
  for (int nt=0; nt<4; ++nt){
    int col = n0 + nt*16 + l15;
    float bv = bias ? bias[col] : 0.f;
    #pragma unroll
    for (int r=0;r<4;r++){
      int row = m0 + w*16 + quad*4 + r;
      float v = accs[nt][r] + bv;
      if (act) v = leaky(v);
      if (Cf) Cf[(size_t)row*N + col] = v;
      if (Ch) Ch[(size_t)row*N + col] = __float2half(v);
    }
  }
}

// -------- GCN aggregation, F=128: 4 waves split edges, ILP-4, optional bias+leaky ----
// padded-bucket CSR: edges of node c live at src[c*MAXDEG .. c*MAXDEG+deg[c])
__device__ __forceinline__ void agg128_unit(const __half* __restrict__ in,
    const int* __restrict__ deg, const int* __restrict__ src,
    __half* __restrict__ outp,
    const float* __restrict__ bias, int act, int c, char* smem){
  int t = threadIdx.x, w = t>>6, lane = t&63;
  int dcc = deg[c];
  float dc = rsqrtf((float)(dcc+1));
  float2 acc = make_float2(0.f, 0.f);
  int e0 = c*MAXDEG, e1 = e0 + dcc;
  for (int eb = e0 + w*4; eb < e1; eb += 16){
    int m = e1 - eb; if (m > 4) m = 4;
    int r[4];
    #pragma unroll
    for (int u=0;u<4;u++) r[u] = src[(u<m) ? eb+u : eb];
    float sc[4]; __half2 hv[4];
    #pragma unroll
    for (int u=0;u<4;u++){
      sc[u] = rsqrtf((float)(deg[r[u]]+1));
      hv[u] = *(const __half2*)(in + (size_t)r[u]*128 + lane*2);
    }
    #pragma unroll
    for (int u=0;u<4;u++){
      if (u < m){
        float2 h = __half22float2(hv[u]);
        acc.x = fmaf(sc[u], h.x, acc.x);
        acc.y = fmaf(sc[u], h.y, acc.y);
      }
    }
  }
  float2 (*red)[64] = (float2(*)[64])smem;
  red[w][lane] = acc;
  __syncthreads();
  if (w == 0){
    float2 s = red[0][lane];
    float2 b1 = red[1][lane], b2 = red[2][lane], b3 = red[3][lane];
    s.x += b1.x + b2.x + b3.x;
    s.y += b1.y + b2.y + b3.y;
    float2 self = __half22float2(*(const __half2*)(in + (size_t)c*128 + lane*2));
    float ox = dc*(dc*self.x + s.x);
    float oy = dc*(dc*self.y + s.y);
    if (act){
      ox = leaky(ox + bias[lane*2]);
      oy = leaky(oy + bias[lane*2+1]);
    }
    *(__half2*)(outp + (size_t)c*128 + lane*2) = __floats2half2_rn(ox, oy);
  }
}

// ------- fused attention (projected 64-dim), wave-per-node, 8-edge ILP, fdot2 --------
__device__ __forceinline__ void attn_unit(const GP& p, int u){
  const int n = NNODES;
  int w = threadIdx.x>>6, lane = threadIdx.x&63;
  int i = u*4 + w;
  int fo = lane*4;
  uint2 qtu = *(const uint2*)(p.qth + (size_t)i*256 + fo);
  h2v q0 = as_h2(qtu.x), q1 = as_h2(qtu.y);
  float4 wbv = *(const float4*)(p.wb + fo);
  uint2 hiu  = *(const uint2*)(p.h2h + (size_t)i*256 + fo);
  float2 hia = __half22float2(*(__half2*)&hiu.x);
  float2 hib = __half22float2(*(__half2*)&hiu.y);
  float pv = hia.x*wbv.x + hia.y*wbv.y + hib.x*wbv.z + hib.y*wbv.w;
  #pragma unroll
  for (int mm=32; mm; mm>>=1) pv += __shfl_xor(pv, mm, 64);
  float Ei = __expf(pv + p.s0p[0]);
  int dri = p.degr[i];
  int e0 = i*MAXDEG, e1 = e0 + dri;
  float acc = 0.f, dsum = 0.f;
  for (int eb = e0; eb < e1; eb += 8){
    int m = e1 - eb; if (m > 8) m = 8;
    int j[8];
    #pragma unroll
    for (int u8=0;u8<8;u8++) j[u8] = p.csrd[(u8<m) ? eb+u8 : eb];
    uint2 hv[8]; float gv[8];
    #pragma unroll
    for (int u8=0;u8<8;u8++){
      hv[u8] = *(const uint2*)(p.h2h + (size_t)j[u8]*256 + fo);
      gv[u8] = __half2float(p.gh[(size_t)j[u8]*64 + lane]);
    }
    float d[8];
    #pragma unroll
    for (int u8=0;u8<8;u8++)
      d[u8] = __builtin_amdgcn_fdot2(q1, as_h2(hv[u8].y),
              __builtin_amdgcn_fdot2(q0, as_h2(hv[u8].x), 0.f, false), false);
    #pragma unroll
    for (int mm=32; mm; mm>>=1){
      #pragma unroll
      for (int u8=0;u8<8;u8++) d[u8] += __shfl_xor(d[u8], mm, 64);
    }
    #pragma unroll
    for (int u8=0;u8<8;u8++){
      if (u8 < m){
        float we = Ei * __expf(d[u8]);
        dsum += we;
        acc = fmaf(we - 1.f, gv[u8], acc);
      }
    }
  }
  float inv = 1.0f / ((float)(n - dri) + dsum);
  p.hw3h[(size_t)i*64 + lane] = __float2half((p.sw3[lane] + acc) * inv);
}

// ------- fused conv3 agg + bias + leaky + residual + LayerNorm + pool atomicMax ------
__device__ __forceinline__ void zp_unit(const GP& p, int c, char* smem){
  int t = threadIdx.x, w = t>>6, lane = t&63;
  int dcc = p.degc[c];
  float dc = rsqrtf((float)(dcc+1));
  float acc = 0.f;
  int e0 = c*MAXDEG, e1 = e0 + dcc;
  for (int eb = e0 + w*4; eb < e1; eb += 16){
    int m = e1 - eb; if (m > 4) m = 4;
    int r[4];
    #pragma unroll
    for (int u=0;u<4;u++) r[u] = p.csrc[(u<m) ? eb+u : eb];
    float sc[4]; __half hval[4];
    #pragma unroll
    for (int u=0;u<4;u++){
      sc[u] = rsqrtf((float)(p.degc[r[u]]+1));
      hval[u] = p.hw3h[(size_t)r[u]*64 + lane];
    }
    #pragma unroll
    for (int u=0;u<4;u++)
      if (u < m) acc = fmaf(sc[u], __half2float(hval[u]), acc);
  }
  float (*red)[64] = (float(*)[64])smem;
  red[w][lane] = acc;
  __syncthreads();
  if (w == 0){
    acc = red[0][lane]+red[1][lane]+red[2][lane]+red[3][lane];
    float self = __half2float(p.hw3h[(size_t)c*64 + lane]);
    float v = leaky(dc*(dc*self + acc) + p.b3[lane]) + p.resid[(size_t)c*64 + lane];
    float s = v;
    #pragma unroll
    for (int mm=32; mm; mm>>=1) s += __shfl_xor(s, mm, 64);
    float mu = s * (1.0f/64.0f);
    float d = v - mu;
    float s2 = d*d;
    #pragma unroll
    for (int mm=32; mm; mm>>=1) s2 += __shfl_xor(s2, mm, 64);
    float zv = d * rsqrtf(s2*(1.0f/64.0f) + 1e-5f) * p.lng[lane] + p.lnb[lane];
    atomicMax(&p.poolpart[(c & 63)*64 + lane], fmap(zv));
  }
}

// ---------------- final: reduce poolpart buckets + 64x16 matvec ----------------
__device__ __forceinline__ void final_unit(const GP& p, char* smem){
  int t = threadIdx.x, f = t & 63, g = t >> 6;
  unsigned (*sm)[64] = (unsigned(*)[64])smem;
  float* pool = (float*)(smem + 1024);
  unsigned mu = 0u;
  for (int b = g; b < 64; b += 4) mu = max(mu, p.poolpart[b*64 + f]);
  sm[g][f] = mu;
  __syncthreads();
  if (g == 0)
    pool[f] = funmap(max(max(sm[0][f],sm[1][f]), max(sm[2][f],sm[3][f])));
  __syncthreads();
  if (t < 16){
    float a = p.bfv[t];
    #pragma unroll
    for (int ff=0; ff<64; ++ff) a = fmaf(pool[ff], p.Wf[ff*16 + t], a);
    p.out[t] = a;
  }
}

// ======================= kernels (one launch per pipeline stage) =====================
__global__ __launch_bounds__(256) void k_pre(GP p){
  __shared__ __align__(16) char smem[SMEM_BYTES];
  pre_unit(p, blockIdx.x, smem);
}

// fused count+scatter into padded buckets (no scan/cursors), co-running with
// xw1 gemm (256 tiles) + Wqkt gemm (16) + resid gemm (128)
__global__ __launch_bounds__(256) void k_sc(GP p){
  __shared__ __align__(16) char smem[SMEM_BYTES];
  _Float16 (*As)[40] = (_Float16(*)[40])smem;
  _Float16 (*Bs)[40] = (_Float16(*)[40])(smem + 5120);
  int b = blockIdx.x;
  if (b < 1024){
    int e = b*256 + threadIdx.x;
    int r = p.ei[e], c = p.ei[NEDGES+e];
    int p1 = atomicAdd(&p.degc[c],1); p.csrc[c*MAXDEG + p1] = r;
    int p2 = atomicAdd(&p.degr[r],1); p.csrd[r*MAXDEG + p2] = c;
  } else if (b < 1280){
    int bb = b - 1024;
    gemm_tile(p.xh, p.W1t, nullptr, nullptr, p.xw1h, nullptr, 128, 128, 0, bb>>1, bb&1, As, Bs, nullptr);
  } else if (b < 1296){
    int bb = b - 1280;             // Wqkt = (Wq@Wk^T)^T = Wk@Wq^T
    gemm_tile(p.Wkh, p.Wqh, nullptr, nullptr, p.Wqkt, nullptr, 256, 256, 0, bb&3, bb>>2, As, Bs, nullptr);
  } else {
    gemm_tile(p.xh, p.Wrt, p.br, p.resid, nullptr, nullptr, 128, 64, 0, b-1296, 0, As, Bs, nullptr);
  }
}

__global__ __launch_bounds__(256) void k_agg(GP p, int which){
  __shared__ __align__(16) char smem[SMEM_BYTES];
  if (which == 0)
    agg128_unit(p.xw1h, p.degc, p.csrc, p.h1h, p.b1, 1, blockIdx.x, smem);
  else
    agg128_unit(p.h1h, p.degc, p.csrc, p.h1ah, nullptr, 0, blockIdx.x, smem);
}

// conv2 transform: h2 = leaky(h1a@W2 + b2)
__global__ __launch_bounds__(256) void k_gemm2(GP p){
  __shared__ __align__(16) char smem[SMEM_BYTES];
  _Float16 (*As)[40] = (_Float16(*)[40])smem;
  _Float16 (*Bs)[40] = (_Float16(*)[40])(smem + 5120);
  int b = blockIdx.x;
  gemm_tile(p.h1ah, p.W2t, p.b2, nullptr, p.h2h, nullptr, 128, 256, 1, b>>2, b&3, As, Bs, nullptr);
}

// G = h2@W3 (+colsum) and qt = h2@Wqk + bqk
__global__ __launch_bounds__(256) void k_mix2(GP p){
  __shared__ __align__(16) char smem[SMEM_BYTES];
  _Float16 (*As)[40] = (_Float16(*)[40])smem;
  _Float16 (*Bs)[40] = (_Float16(*)[40])(smem + 5120);
  float* cs = (float*)(smem + 10240);
  int b = blockIdx.x;
  if (b < 128) gemm_tile(p.h2h, p.W3t, nullptr, nullptr, p.gh, p.sw3, 256, 64, 0, b, 0, As, Bs, cs);
  else {
    int bb = b - 128;
    gemm_tile(p.h2h, p.Wqkt, p.bqk, nullptr, p.qth, nullptr, 256, 256, 0, bb>>2, bb&3, As, Bs, cs);
  }
}

__global__ __launch_bounds__(256) void k_attn(GP p){ attn_unit(p, blockIdx.x); }

__global__ __launch_bounds__(256) void k_zp(GP p){
  __shared__ __align__(16) char smem[SMEM_BYTES];
  zp_unit(p, blockIdx.x, smem);
}

__global__ __launch_bounds__(256) void k_final(GP p){
  __shared__ __align__(16) char smem[SMEM_BYTES];
  final_unit(p, smem);
}

extern "C" void kernel_launch(void* const* d_in, const int* in_sizes, int n_in,
                              void* d_out, int out_size, void* d_ws, size_t ws_size,
                              hipStream_t stream){
  const int n = NNODES, E = NEDGES;
  char* ws = (char*)d_ws; size_t off = 0;
  auto alloc = [&](size_t bytes)->void*{
    void* pp = ws + off; off += (bytes + 255) & ~(size_t)255; return pp;
  };
  GP p;
  p.x   = (const float*)d_in[0];
  p.ei  = (const int*)d_in[1];
  p.W1  = (const float*)d_in[2];  p.b1 = (const float*)d_in[3];
  p.W2  = (const float*)d_in[4];  p.b2 = (const float*)d_in[5];
  p.W3  = (const float*)d_in[6];  p.b3 = (const float*)d_in[7];
  p.Wk  = (const float*)d_in[8];  p.bk = (const float*)d_in[9];
  p.Wq  = (const float*)d_in[10]; p.bq = (const float*)d_in[11];
  p.Wr  = (const float*)d_in[12]; p.br = (const float*)d_in[13];
  p.lng = (const float*)d_in[14]; p.lnb = (const float*)d_in[15];
  p.Wf  = (const float*)d_in[16]; p.bfv = (const float*)d_in[17];
  p.out = (float*)d_out;

  p.xh   = (__half*)alloc((size_t)n*128*2);
  p.xw1h = (__half*)alloc((size_t)n*128*2);
  p.h1h  = (__half*)alloc((size_t)n*128*2);
  p.h1ah = (__half*)alloc((size_t)n*128*2);
  p.h2h  = (__half*)alloc((size_t)n*256*2);
  p.qth  = (__half*)alloc((size_t)n*256*2);
  p.gh   = (__half*)alloc((size_t)n*64*2);
  p.hw3h = (__half*)alloc((size_t)n*64*2);
  p.resid= (float*)alloc((size_t)n*64*4);
  p.sw3  = (float*)alloc(64*4);
  p.Wqh  = (__half*)alloc(256*256*2);
  p.Wkh  = (__half*)alloc(256*256*2);
  p.Wqkt = (__half*)alloc(256*256*2);
  p.Wrt  = (__half*)alloc(128*64*2);
  p.W1t  = (__half*)alloc(128*128*2);
  p.W2t  = (__half*)alloc(128*256*2);
  p.W3t  = (__half*)alloc(256*64*2);
  p.bqk  = (float*)alloc(256*4);
  p.wb   = (float*)alloc(256*4);
  p.s0p  = (float*)alloc(4);
  p.degc = (int*)alloc((size_t)n*4);
  p.degr = (int*)alloc((size_t)n*4);
  p.csrc = (int*)alloc((size_t)n*MAXDEG*4);
  p.csrd = (int*)alloc((size_t)n*MAXDEG*4);
  p.poolpart = (unsigned*)alloc(64*64*4);

  k_pre  <<<dim3(1777), 256, 0, stream>>>(p);   // conversions/transposes/zero/smallvec
  k_sc   <<<dim3(1424), 256, 0, stream>>>(p);   // fused count+scatter + 3 gemms
  k_agg  <<<dim3(n),    256, 0, stream>>>(p, 0);// conv1 aggregate + bias + leaky
  k_agg  <<<dim3(n),    256, 0, stream>>>(p, 1);// conv2 aggregate
  k_gemm2<<<dim3(512),  256, 0, stream>>>(p);   // h2 = leaky(h1a@W2+b2)
  k_mix2 <<<dim3(640),  256, 0, stream>>>(p);   // G=h2@W3 (+colsum), qt=h2@Wqk+bqk
  k_attn <<<dim3(n/4),  256, 0, stream>>>(p);   // fused attention
  k_zp   <<<dim3(n),    256, 0, stream>>>(p);   // conv3 agg+resid+LN+pool
  k_final<<<dim3(1),    256, 0, stream>>>(p);   // bucket reduce + matvec
}

// Round 5
// 216.745 us; speedup vs baseline: 4.4450x; 1.0354x over previous
//
#include <hip/hip_runtime.h>
#include <hip/hip_fp16.h>
#include <cstdint>
#include <cstddef>

#define NNODES 8192
#define NEDGES 262144
#define MAXDEG 96          // mean degree 32, sigma 5.7 -> +11 sigma headroom
#define SMEM_BYTES 10496   // max over phases: gemm As(5120)+Bs(5120)+cs(256)

typedef _Float16 f16x8 __attribute__((ext_vector_type(8)));
typedef _Float16 h2v   __attribute__((ext_vector_type(2)));
typedef float    f32x4 __attribute__((ext_vector_type(4)));

__device__ __forceinline__ float leaky(float v){ return v > 0.f ? v : 0.01f*v; }

__device__ __forceinline__ unsigned fmap(float f){
  unsigned u = __float_as_uint(f);
  return (u & 0x80000000u) ? ~u : (u | 0x80000000u);
}
__device__ __forceinline__ float funmap(unsigned u){
  return (u & 0x80000000u) ? __uint_as_float(u & 0x7FFFFFFFu) : __uint_as_float(~u);
}
__device__ __forceinline__ h2v as_h2(unsigned u){
  union{ unsigned x; h2v h; } c; c.x = u; return c.h;
}

// ---------------- all device pointers in one struct (single kernel arg) ----------
struct GP {
  const float *x; const int *ei;
  const float *W1,*b1,*W2,*b2,*W3,*b3,*Wk,*bk,*Wq,*bq,*Wr,*br,*lng,*lnb,*Wf,*bfv;
  float* out;
  __half *xh,*xw1h,*h1h,*h1ah,*h2h,*qth,*gh,*hw3h;
  float *resid,*sw3;
  __half *Wqh,*Wkh,*Wqkt,*Wrt,*W1t,*W2t,*W3t;
  float *bqk,*wb,*s0p;
  int *degc,*degr,*csrc,*csrd;
  unsigned* poolpart;
};

// ================= pre unit: conversions / transposes / zeroing / small vectors ====
__device__ __forceinline__ void pre_unit(const GP& p, int b, char* smem){
  int t = threadIdx.x;
  if (b < 1024){
    int base = (b*256 + t)*4;
    float4 xv = *(const float4*)(p.x + base);
    uint2 o;
    *(__half2*)&o.x = __floats2half2_rn(xv.x, xv.y);
    *(__half2*)&o.y = __floats2half2_rn(xv.z, xv.w);
    *(uint2*)(p.xh + base) = o;
  } else if (b < 1088){
    int base = ((b-1024)*256 + t)*4;
    float4 v = *(const float4*)(p.Wq + base);
    uint2 o;
    *(__half2*)&o.x = __floats2half2_rn(v.x, v.y);
    *(__half2*)&o.y = __floats2half2_rn(v.z, v.w);
    *(uint2*)(p.Wqh + base) = o;
  } else if (b < 1152){
    int base = ((b-1088)*256 + t)*4;
    float4 v = *(const float4*)(p.Wk + base);
    uint2 o;
    *(__half2*)&o.x = __floats2half2_rn(v.x, v.y);
    *(__half2*)&o.y = __floats2half2_rn(v.z, v.w);
    *(uint2*)(p.Wkh + base) = o;
  } else if (b < 1184){         // Wr[128][64] -> Wrt[64][128]
    int idx = (b-1152)*256 + t;
    int nn = idx >> 7, k = idx & 127;
    p.Wrt[idx] = __float2half(p.Wr[k*64 + nn]);
  } else if (b < 1248){         // W1[128][128] -> W1t[128][128]
    int idx = (b-1184)*256 + t;
    int nn = idx >> 7, k = idx & 127;
    p.W1t[idx] = __float2half(p.W1[k*128 + nn]);
  } else if (b < 1376){         // W2[128][256] -> W2t[256][128]
    int idx = (b-1248)*256 + t;
    int nn = idx >> 7, k = idx & 127;
    p.W2t[idx] = __float2half(p.W2[k*256 + nn]);
  } else if (b < 1440){         // W3[256][64] -> W3t[64][256]
    int idx = (b-1376)*256 + t;
    int nn = idx >> 8, k = idx & 255;
    p.W3t[idx] = __float2half(p.W3[k*64 + nn]);
  } else if (b < 1504){
    int idx = (b-1440)*256 + t;
    if (idx < 8192) p.degc[idx]=0; else p.degr[idx-8192]=0;
  } else if (b < 1520){
    p.poolpart[(b-1504)*256 + t] = 0u;
  } else if (b == 1520){
    if (t < 64) p.sw3[t]=0.f;
  } else {                      // smallvec: coalesced row read + block reduce
    int c = b - 1521;
    float* ra = (float*)smem; float* rb = ra + 256; float* rc = rb + 256;
    ra[t] = p.Wk[c*256 + t] * p.bq[t];
    rb[t] = p.Wq[c*256 + t] * p.bk[t];
    if (c == 0) rc[t] = p.bq[t]*p.bk[t];
    __syncthreads();
    for (int off=128; off; off>>=1){
      if (t < off){
        ra[t] += ra[t+off];
        rb[t] += rb[t+off];
        if (c == 0) rc[t] += rc[t+off];
      }
      __syncthreads();
    }
    if (t == 0){
      p.bqk[c] = ra[0];
      p.wb[c]  = rb[0];
      if (c == 0) p.s0p[0] = rc[0];
    }
  }
}

// ---------------- MFMA GEMM tile (device): C64x64 = A[.,K] @ Bt[.,K]^T ----------------
__device__ __forceinline__ void gemm_tile(const __half* __restrict__ A,
    const __half* __restrict__ Bt, const float* __restrict__ bias,
    float* __restrict__ Cf, __half* __restrict__ Ch, float* __restrict__ csum,
    int K, int N, int act, int bx, int by,
    _Float16 (*As)[40], _Float16 (*Bs)[40], float* cs){
  int t = threadIdx.x, w = t>>6, lane = t&63;
  int m0 = bx*64, n0 = by*64;
  int quad = lane>>4, l15 = lane&15;
  int srow = t>>2, soff = (t&3)*8;
  f32x4 acc0 = {0.f,0.f,0.f,0.f}, acc1 = acc0, acc2 = acc0, acc3 = acc0;
  for (int k0 = 0; k0 < K; k0 += 32){
    *(uint4*)&As[srow][soff] = *(const uint4*)(A  + (size_t)(m0+srow)*K + k0 + soff);
    *(uint4*)&Bs[srow][soff] = *(const uint4*)(Bt + (size_t)(n0+srow)*K + k0 + soff);
    __syncthreads();
    f16x8 af = *(const f16x8*)&As[w*16 + l15][quad*8];
    f16x8 b0 = *(const f16x8*)&Bs[ 0 + l15][quad*8];
    f16x8 b1 = *(const f16x8*)&Bs[16 + l15][quad*8];
    f16x8 b2 = *(const f16x8*)&Bs[32 + l15][quad*8];
    f16x8 b3 = *(const f16x8*)&Bs[48 + l15][quad*8];
    acc0 = __builtin_amdgcn_mfma_f32_16x16x32_f16(af, b0, acc0, 0,0,0);
    acc1 = __builtin_amdgcn_mfma_f32_16x16x32_f16(af, b1, acc1, 0,0,0);
    acc2 = __builtin_amdgcn_mfma_f32_16x16x32_f16(af, b2, acc2, 0,0,0);
    acc3 = __builtin_amdgcn_mfma_f32_16x16x32_f16(af, b3, acc3, 0,0,0);
    __syncthreads();
  }
  f32x4 accs[4] = {acc0, acc1, acc2, acc3};
  if (csum){
    if (t < 64) cs[t] = 0.f;
    __syncthreads();
    #pragma unroll
    for (int nt=0; nt<4; ++nt){
      float pp = accs[nt][0]+accs[nt][1]+accs[nt][2]+accs[nt][3];
      atomicAdd(&cs[nt*16 + l15], pp);
    }
    __syncthreads();
    if (t < 64) atomicAdd(&csum[n0 + t], cs[t]);
  }
  #pragma unroll
  for (int nt=0; nt<4; ++nt){
    int col = n0 + nt*16 + l15;
    float bv = bias ? bias[col] : 0.f;
    #pragma unroll
    for (int r=0;r<4;r++){
      int row = m0 + w*16 + quad*4 + r;
      float v = accs[nt][r] + bv;
      if (act) v = leaky(v);
      if (Cf) Cf[(size_t)row*N + col] = v;
      if (Ch) Ch[(size_t)row*N + col] = __float2half(v);
    }
  }
}

// -------- GCN aggregation F=128, WAVE-PER-NODE, ILP-8 over padded buckets ---------
// INS: input rows pre-scaled by their d (skip per-edge deg load)
// OUTS: multiply final value by d_c before store (pre-scale for the next agg)
// ACT: add bias + leaky
template<int INS, int OUTS, int ACT>
__device__ __forceinline__ void agg128w(const __half* __restrict__ in,
    const int* __restrict__ deg, const int* __restrict__ src,
    __half* __restrict__ outp, const float* __restrict__ bias, int i){
  int lane = threadIdx.x & 63;
  int dcc = deg[i];
  float dc = rsqrtf((float)(dcc+1));
  int e0 = i*MAXDEG, e1 = e0 + dcc;
  float2 acc = make_float2(0.f, 0.f);
  for (int eb = e0; eb < e1; eb += 8){
    int m = e1 - eb; if (m > 8) m = 8;
    int r[8];
    #pragma unroll
    for (int u=0;u<8;u++) r[u] = src[(u<m) ? eb+u : eb];
    __half2 hv[8]; float sc[8];
    #pragma unroll
    for (int u=0;u<8;u++){
      hv[u] = *(const __half2*)(in + (size_t)r[u]*128 + lane*2);
      sc[u] = INS ? 1.f : rsqrtf((float)(deg[r[u]]+1));
    }
    #pragma unroll
    for (int u=0;u<8;u++){
      if (u < m){
        float2 h = __half22float2(hv[u]);
        if (INS){ acc.x += h.x; acc.y += h.y; }
        else { acc.x = fmaf(sc[u], h.x, acc.x); acc.y = fmaf(sc[u], h.y, acc.y); }
      }
    }
  }
  float2 self = __half22float2(*(const __half2*)(in + (size_t)i*128 + lane*2));
  float ss = INS ? 1.f : dc;
  float ox = dc*(ss*self.x + acc.x);
  float oy = dc*(ss*self.y + acc.y);
  if (ACT){
    ox = leaky(ox + bias[lane*2]);
    oy = leaky(oy + bias[lane*2+1]);
  }
  if (OUTS){ ox *= dc; oy *= dc; }
  *(__half2*)(outp + (size_t)i*128 + lane*2) = __floats2half2_rn(ox, oy);
}

// ------- fused attention (projected 64-dim), wave-per-node, 8-edge ILP, fdot2 --------
// writes hw3h pre-scaled by d_i (column-degree norm) so k_zp skips per-edge scales
__device__ __forceinline__ void attn_unit(const GP& p, int u){
  const int n = NNODES;
  int w = threadIdx.x>>6, lane = threadIdx.x&63;
  int i = u*4 + w;
  int fo = lane*4;
  uint2 qtu = *(const uint2*)(p.qth + (size_t)i*256 + fo);
  h2v q0 = as_h2(qtu.x), q1 = as_h2(qtu.y);
  float4 wbv = *(const float4*)(p.wb + fo);
  uint2 hiu  = *(const uint2*)(p.h2h + (size_t)i*256 + fo);
  float2 hia = __half22float2(*(__half2*)&hiu.x);
  float2 hib = __half22float2(*(__half2*)&hiu.y);
  float pv = hia.x*wbv.x + hia.y*wbv.y + hib.x*wbv.z + hib.y*wbv.w;
  #pragma unroll
  for (int mm=32; mm; mm>>=1) pv += __shfl_xor(pv, mm, 64);
  float Ei = __expf(pv + p.s0p[0]);
  int dri = p.degr[i];
  int e0 = i*MAXDEG, e1 = e0 + dri;
  float acc = 0.f, dsum = 0.f;
  for (int eb = e0; eb < e1; eb += 8){
    int m = e1 - eb; if (m > 8) m = 8;
    int j[8];
    #pragma unroll
    for (int u8=0;u8<8;u8++) j[u8] = p.csrd[(u8<m) ? eb+u8 : eb];
    uint2 hv[8]; float gv[8];
    #pragma unroll
    for (int u8=0;u8<8;u8++){
      hv[u8] = *(const uint2*)(p.h2h + (size_t)j[u8]*256 + fo);
      gv[u8] = __half2float(p.gh[(size_t)j[u8]*64 + lane]);
    }
    float d[8];
    #pragma unroll
    for (int u8=0;u8<8;u8++)
      d[u8] = __builtin_amdgcn_fdot2(q1, as_h2(hv[u8].y),
              __builtin_amdgcn_fdot2(q0, as_h2(hv[u8].x), 0.f, false), false);
    #pragma unroll
    for (int mm=32; mm; mm>>=1){
      #pragma unroll
      for (int u8=0;u8<8;u8++) d[u8] += __shfl_xor(d[u8], mm, 64);
    }
    #pragma unroll
    for (int u8=0;u8<8;u8++){
      if (u8 < m){
        float we = Ei * __expf(d[u8]);
        dsum += we;
        acc = fmaf(we - 1.f, gv[u8], acc);
      }
    }
  }
  float inv = 1.0f / ((float)(n - dri) + dsum);
  float di = rsqrtf((float)(p.degc[i]+1));
  p.hw3h[(size_t)i*64 + lane] = __float2half(di * (p.sw3[lane] + acc) * inv);
}

// ------- conv3 agg (pre-scaled input) + bias + leaky + residual + LN + pool ---------
// WAVE-PER-NODE, ILP-8, no LDS / no syncthreads
__device__ __forceinline__ void zp_wave(const GP& p, int c){
  int lane = threadIdx.x & 63;
  int dcc = p.degc[c];
  float dc = rsqrtf((float)(dcc+1));
  float acc = 0.f;
  int e0 = c*MAXDEG, e1 = e0 + dcc;
  for (int eb = e0; eb < e1; eb += 8){
    int m = e1 - eb; if (m > 8) m = 8;
    int r[8];
    #pragma unroll
    for (int u=0;u<8;u++) r[u] = p.csrc[(u<m) ? eb+u : eb];
    __half hval[8];
    #pragma unroll
    for (int u=0;u<8;u++) hval[u] = p.hw3h[(size_t)r[u]*64 + lane];
    #pragma unroll
    for (int u=0;u<8;u++)
      if (u < m) acc += __half2float(hval[u]);
  }
  float self = __half2float(p.hw3h[(size_t)c*64 + lane]);   // pre-scaled by d_c
  float v = leaky(dc*(self + acc) + p.b3[lane]) + p.resid[(size_t)c*64 + lane];
  float s = v;
  #pragma unroll
  for (int mm=32; mm; mm>>=1) s += __shfl_xor(s, mm, 64);
  float mu = s * (1.0f/64.0f);
  float d = v - mu;
  float s2 = d*d;
  #pragma unroll
  for (int mm=32; mm; mm>>=1) s2 += __shfl_xor(s2, mm, 64);
  float zv = d * rsqrtf(s2*(1.0f/64.0f) + 1e-5f) * p.lng[lane] + p.lnb[lane];
  atomicMax(&p.poolpart[(c & 63)*64 + lane], fmap(zv));
}

// ---------------- final: reduce poolpart buckets + 64x16 matvec ----------------
__device__ __forceinline__ void final_unit(const GP& p, char* smem){
  int t = threadIdx.x, f = t & 63, g = t >> 6;
  unsigned (*sm)[64] = (unsigned(*)[64])smem;
  float* pool = (float*)(smem + 1024);
  unsigned mu = 0u;
  for (int b = g; b < 64; b += 4) mu = max(mu, p.poolpart[b*64 + f]);
  sm[g][f] = mu;
  __syncthreads();
  if (g == 0)
    pool[f] = funmap(max(max(sm[0][f],sm[1][f]), max(sm[2][f],sm[3][f])));
  __syncthreads();
  if (t < 16){
    float a = p.bfv[t];
    #pragma unroll
    for (int ff=0; ff<64; ++ff) a = fmaf(pool[ff], p.Wf[ff*16 + t], a);
    p.out[t] = a;
  }
}

// ======================= kernels (one launch per pipeline stage) =====================
__global__ __launch_bounds__(256) void k_pre(GP p){
  __shared__ __align__(16) char smem[SMEM_BYTES];
  pre_unit(p, blockIdx.x, smem);
}

// fused count+scatter into padded buckets, co-running with xw1/Wqkt/resid gemms
__global__ __launch_bounds__(256) void k_sc(GP p){
  __shared__ __align__(16) char smem[SMEM_BYTES];
  _Float16 (*As)[40] = (_Float16(*)[40])smem;
  _Float16 (*Bs)[40] = (_Float16(*)[40])(smem + 5120);
  int b = blockIdx.x;
  if (b < 1024){
    int e = b*256 + threadIdx.x;
    int r = p.ei[e], c = p.ei[NEDGES+e];
    int p1 = atomicAdd(&p.degc[c],1); p.csrc[c*MAXDEG + p1] = r;
    int p2 = atomicAdd(&p.degr[r],1); p.csrd[r*MAXDEG + p2] = c;
  } else if (b < 1280){
    int bb = b - 1024;
    gemm_tile(p.xh, p.W1t, nullptr, nullptr, p.xw1h, nullptr, 128, 128, 0, bb>>1, bb&1, As, Bs, nullptr);
  } else if (b < 1296){
    int bb = b - 1280;             // Wqkt = (Wq@Wk^T)^T = Wk@Wq^T
    gemm_tile(p.Wkh, p.Wqh, nullptr, nullptr, p.Wqkt, nullptr, 256, 256, 0, bb&3, bb>>2, As, Bs, nullptr);
  } else {
    gemm_tile(p.xh, p.Wrt, p.br, p.resid, nullptr, nullptr, 128, 64, 0, b-1296, 0, As, Bs, nullptr);
  }
}

// conv1 aggregate (+bias+leaky), output pre-scaled by d_c -> h1'
__global__ __launch_bounds__(256) void k_agg0(GP p){
  int i = blockIdx.x*4 + (threadIdx.x>>6);
  agg128w<0,1,1>(p.xw1h, p.degc, p.csrc, p.h1h, p.b1, i);
}
// conv2 aggregate on pre-scaled input, unscaled output
__global__ __launch_bounds__(256) void k_agg1(GP p){
  int i = blockIdx.x*4 + (threadIdx.x>>6);
  agg128w<1,0,0>(p.h1h, p.degc, p.csrc, p.h1ah, nullptr, i);
}

// conv2 transform: h2 = leaky(h1a@W2 + b2)
__global__ __launch_bounds__(256) void k_gemm2(GP p){
  __shared__ __align__(16) char smem[SMEM_BYTES];
  _Float16 (*As)[40] = (_Float16(*)[40])smem;
  _Float16 (*Bs)[40] = (_Float16(*)[40])(smem + 5120);
  int b = blockIdx.x;
  gemm_tile(p.h1ah, p.W2t, p.b2, nullptr, p.h2h, nullptr, 128, 256, 1, b>>2, b&3, As, Bs, nullptr);
}

// G = h2@W3 (+colsum) and qt = h2@Wqk + bqk
__global__ __launch_bounds__(256) void k_mix2(GP p){
  __shared__ __align__(16) char smem[SMEM_BYTES];
  _Float16 (*As)[40] = (_Float16(*)[40])smem;
  _Float16 (*Bs)[40] = (_Float16(*)[40])(smem + 5120);
  float* cs = (float*)(smem + 10240);
  int b = blockIdx.x;
  if (b < 128) gemm_tile(p.h2h, p.W3t, nullptr, nullptr, p.gh, p.sw3, 256, 64, 0, b, 0, As, Bs, cs);
  else {
    int bb = b - 128;
    gemm_tile(p.h2h, p.Wqkt, p.bqk, nullptr, p.qth, nullptr, 256, 256, 0, bb>>2, bb&3, As, Bs, cs);
  }
}

__global__ __launch_bounds__(256) void k_attn(GP p){ attn_unit(p, blockIdx.x); }

__global__ __launch_bounds__(256) void k_zp(GP p){
  int c = blockIdx.x*4 + (threadIdx.x>>6);
  zp_wave(p, c);
}

__global__ __launch_bounds__(256) void k_final(GP p){
  __shared__ __align__(16) char smem[SMEM_BYTES];
  final_unit(p, smem);
}

extern "C" void kernel_launch(void* const* d_in, const int* in_sizes, int n_in,
                              void* d_out, int out_size, void* d_ws, size_t ws_size,
                              hipStream_t stream){
  const int n = NNODES, E = NEDGES;
  char* ws = (char*)d_ws; size_t off = 0;
  auto alloc = [&](size_t bytes)->void*{
    void* pp = ws + off; off += (bytes + 255) & ~(size_t)255; return pp;
  };
  GP p;
  p.x   = (const float*)d_in[0];
  p.ei  = (const int*)d_in[1];
  p.W1  = (const float*)d_in[2];  p.b1 = (const float*)d_in[3];
  p.W2  = (const float*)d_in[4];  p.b2 = (const float*)d_in[5];
  p.W3  = (const float*)d_in[6];  p.b3 = (const float*)d_in[7];
  p.Wk  = (const float*)d_in[8];  p.bk = (const float*)d_in[9];
  p.Wq  = (const float*)d_in[10]; p.bq = (const float*)d_in[11];
  p.Wr  = (const float*)d_in[12]; p.br = (const float*)d_in[13];
  p.lng = (const float*)d_in[14]; p.lnb = (const float*)d_in[15];
  p.Wf  = (const float*)d_in[16]; p.bfv = (const float*)d_in[17];
  p.out = (float*)d_out;

  p.xh   = (__half*)alloc((size_t)n*128*2);
  p.xw1h = (__half*)alloc((size_t)n*128*2);
  p.h1h  = (__half*)alloc((size_t)n*128*2);
  p.h1ah = (__half*)alloc((size_t)n*128*2);
  p.h2h  = (__half*)alloc((size_t)n*256*2);
  p.qth  = (__half*)alloc((size_t)n*256*2);
  p.gh   = (__half*)alloc((size_t)n*64*2);
  p.hw3h = (__half*)alloc((size_t)n*64*2);
  p.resid= (float*)alloc((size_t)n*64*4);
  p.sw3  = (float*)alloc(64*4);
  p.Wqh  = (__half*)alloc(256*256*2);
  p.Wkh  = (__half*)alloc(256*256*2);
  p.Wqkt = (__half*)alloc(256*256*2);
  p.Wrt  = (__half*)alloc(128*64*2);
  p.W1t  = (__half*)alloc(128*128*2);
  p.W2t  = (__half*)alloc(128*256*2);
  p.W3t  = (__half*)alloc(256*64*2);
  p.bqk  = (float*)alloc(256*4);
  p.wb   = (float*)alloc(256*4);
  p.s0p  = (float*)alloc(4);
  p.degc = (int*)alloc((size_t)n*4);
  p.degr = (int*)alloc((size_t)n*4);
  p.csrc = (int*)alloc((size_t)n*MAXDEG*4);
  p.csrd = (int*)alloc((size_t)n*MAXDEG*4);
  p.poolpart = (unsigned*)alloc(64*64*4);

  k_pre  <<<dim3(1777), 256, 0, stream>>>(p);   // conversions/transposes/zero/smallvec
  k_sc   <<<dim3(1424), 256, 0, stream>>>(p);   // fused count+scatter + 3 gemms
  k_agg0 <<<dim3(n/4),  256, 0, stream>>>(p);   // conv1 agg + bias + leaky, pre-scaled out
  k_agg1 <<<dim3(n/4),  256, 0, stream>>>(p);   // conv2 agg (pre-scaled in)
  k_gemm2<<<dim3(512),  256, 0, stream>>>(p);   // h2 = leaky(h1a@W2+b2)
  k_mix2 <<<dim3(640),  256, 0, stream>>>(p);   // G=h2@W3 (+colsum), qt=h2@Wqk+bqk
  k_attn <<<dim3(n/4),  256, 0, stream>>>(p);   // fused attention (pre-scaled out)
  k_zp   <<<dim3(n/4),  256, 0, stream>>>(p);   // conv3 agg+resid+LN+pool (wave/node)
  k_final<<<dim3(1),    256, 0, stream>>>(p);   // bucket reduce + matvec
}